// Round 2
// baseline (253.329 us; speedup 1.0000x reference)
//
#include <hip/hip_runtime.h>
#include <math.h>

// ---------------- problem constants ----------------
constexpr int BATCH = 4;
constexpr int IMG_H = 512, IMG_W = 512;
constexpr int IMG_HW = IMG_H * IMG_W;          // 262144
constexpr int PSTR = BATCH * IMG_HW;           // p-plane stride 1048576

// ---------------- workspace layout (floats) ----------------
constexpr size_t O_PA   = 0;                       // p ping [2][4][512][512] (also split-K partial arena)
constexpr size_t O_PB   = O_PA + 2 * (size_t)PSTR; // p pong
constexpr size_t O_DEN  = O_PB + 2 * (size_t)PSTR; // denoised [4][512][512]
constexpr size_t O_A1   = O_DEN + (size_t)PSTR;    // arena1 (8388608 floats; also head-partial arena)
constexpr size_t O_A2   = O_A1 + 8388608;          // arena2 (2097152 floats)
constexpr size_t O_WT1  = O_A2 + 2097152;          // wT pw1  [32][64]
constexpr size_t O_WT2  = O_WT1 + 32 * 64;
constexpr size_t O_WT3  = O_WT2 + 64 * 128;
constexpr size_t O_WT4  = O_WT3 + 128 * 256;
constexpr size_t O_WTH  = O_WT4 + 256 * 512;
constexpr size_t O_WCOMB= O_WTH + 512 * 1280;      // [1280]
constexpr size_t O_BCOMB= O_WCOMB + 1280;          // [1]
constexpr size_t O_S    = O_BCOMB + 4;             // s field [4][16][16]
constexpr size_t WS_FLOATS = O_S + 1024;

// fast-math device helpers (1-ulp HW ops; validated absmax-neutral in R1)
__device__ __forceinline__ float fast_rcp(float x) { return __builtin_amdgcn_rcpf(x); }
__device__ __forceinline__ float fast_sqrt(float x) { return __builtin_amdgcn_sqrtf(x); }
__device__ __forceinline__ float silu_f(float x) {
    float e = __builtin_amdgcn_exp2f(-1.44269504088896f * x);
    return x * fast_rcp(1.0f + e);
}
__device__ __forceinline__ int clampi(int v, int lo, int hi) {
    return v < lo ? lo : (v > hi ? hi : v);
}

// ---------------- TV Chambolle: register-resident, shuffle-exchange ----------------
// R2: ROWS 7->6 (48-row span, 28 valid rows, grid y=19): same total work (+2%),
// lower VGPR so 4 blocks/CU (8 waves/SIMD, the cap) becomes reachable — TV is
// latency-bound, occupancy is the lever. prep (weight transposes) is merged
// into the FIRST launch as 96 independent extra blocks (by >= 19): removes one
// serial dispatch; prep touches only weight arenas, TV only p/img.
template <int NST, bool FIRST, bool LAST>
__global__ __launch_bounds__(512) void tv_reg(const float* __restrict__ img,
                                              const float* __restrict__ pin,
                                              float* __restrict__ pout,
                                              const float* __restrict__ pw1,
                                              const float* __restrict__ pw2,
                                              const float* __restrict__ pw3,
                                              const float* __restrict__ pw4,
                                              const float* __restrict__ headw,
                                              const float* __restrict__ projw,
                                              const float* __restrict__ projb,
                                              const float* __restrict__ finalw,
                                              float* __restrict__ ws) {
    constexpr int ROWS = 6, NW = 8, HL = 10, TC = 44, TR = 28;
    constexpr int TVY = 19;
    __shared__ float bndP[512], bndO[512];

    if constexpr (FIRST) {
        if (blockIdx.y >= TVY) {
            // ---- prep branch: 96 blocks, grid-stride over 814 work tiles ----
            __shared__ float tt[32][33];
            const int tid = threadIdx.x;
            const int pid = ((blockIdx.y - TVY) * 4 + blockIdx.z) * 12 + blockIdx.x; // [0,96)
            for (int t = pid; t < 814; t += 96) {
                const float* src = nullptr; float* dst = nullptr;
                int C = 0, R = 0, tr = 0, tc = 0;
                if (t < 640) {        // head: 1280(oc) x 512(ic) -> [512][1280]
                    src = headw; dst = ws + O_WTH; R = 1280; C = 512; tr = t >> 4; tc = t & 15;
                } else if (t < 768) { // pw4: 512 x 256 -> [256][512]
                    int e = t - 640; src = pw4; dst = ws + O_WT4; R = 512; C = 256; tr = e >> 3; tc = e & 7;
                } else if (t < 800) { // pw3: 256 x 128 -> [128][256]
                    int e = t - 768; src = pw3; dst = ws + O_WT3; R = 256; C = 128; tr = e >> 2; tc = e & 3;
                } else if (t < 808) { // pw2: 128 x 64 -> [64][128]
                    int e = t - 800; src = pw2; dst = ws + O_WT2; R = 128; C = 64; tr = e >> 1; tc = e & 1;
                } else if (t < 810) { // pw1: 64 x 32 -> [32][64]
                    int e = t - 808; src = pw1; dst = ws + O_WT1; R = 64; C = 32; tr = e; tc = 0;
                }
                const int tx = tid & 31, ty = tid >> 5;       // 32 x 16
                __syncthreads();                              // WAR on tt across t-iterations
                if (src) {
#pragma unroll
                    for (int j = 0; j < 2; ++j)
                        tt[ty + j * 16][tx] =
                            src[(size_t)(tr * 32 + ty + j * 16) * C + tc * 32 + tx];
                }
                __syncthreads();
                if (src) {
#pragma unroll
                    for (int j = 0; j < 2; ++j)
                        dst[(size_t)(tc * 32 + ty + j * 16) * R + tr * 32 + tx] =
                            tt[tx][ty + j * 16];
                } else if (t < 813) {                         // wcomb chunks of 512
                    int k = (t - 810) * 512 + tid;
                    if (k < 1280) {
                        float a = 0.0f;
                        for (int ch = 0; ch < 64; ++ch)
                            a = fmaf(finalw[ch], projw[ch * 1280 + k], a);
                        ws[O_WCOMB + k] = a;
                    }
                } else {                                      // t == 813: bcomb
                    if (tid == 0) {
                        float a = 0.0f;
                        for (int ch = 0; ch < 64; ++ch) a = fmaf(finalw[ch], projb[ch], a);
                        ws[O_BCOMB] = a;
                    }
                }
            }
            return;
        }
    }

    const int tid = threadIdx.x;
    const int lane = tid & 63, w = tid >> 6;
    const int b = blockIdx.z;
    const int r0 = blockIdx.y * TR, c0 = blockIdx.x * TC;
    const int gj = c0 - HL + lane;
    const int gjc = clampi(gj, 0, 511);
    const int gib = r0 - HL + w * ROWS;
    const float* I = img + b * IMG_HW;
    const bool interior = (r0 - HL >= 1) && (r0 + NW * ROWS - HL <= 511) &&
                          (c0 - HL >= 1) && (c0 + 64 - HL <= 511);

    float rim[ROWS], rp0[ROWS], rp1[ROWS], ro[ROWS];
#pragma unroll
    for (int k = 0; k < ROWS; ++k) {
        int gi = clampi(gib + k, 0, 511);
        rim[k] = I[(gi << 9) + gjc];
    }
    if (!FIRST) {
        const float* P0 = pin + b * IMG_HW;
        const float* P1 = pin + PSTR + b * IMG_HW;
#pragma unroll
        for (int k = 0; k < ROWS; ++k) {
            int gi = clampi(gib + k, 0, 511);
            rp0[k] = P0[(gi << 9) + gjc];
            rp1[k] = P1[(gi << 9) + gjc];
        }
    }
    const bool gjpos = (gj > 0), gjlt = (gj < 511);

    int s0 = 0;
    if (FIRST) {
        // stage 0 specialized: p == 0  =>  out-field == img
        bndO[tid] = rim[0];
        __syncthreads();
        float odn = (w < NW - 1) ? bndO[tid + 64] : 0.0f;
        if (interior) {
#pragma unroll
            for (int k = 0; k < ROWS; ++k) {
                float oR = __shfl_down(rim[k], 1);
                float od = (k < ROWS - 1) ? rim[k + 1] : odn;
                float gy = od - rim[k];
                float gx = oR - rim[k];
                float inv = fast_rcp(fmaf(2.5f, fast_sqrt(fmaf(gy, gy, gx * gx)), 1.0f));
                rp0[k] = -0.25f * gy * inv;
                rp1[k] = -0.25f * gx * inv;
            }
        } else {
#pragma unroll
            for (int k = 0; k < ROWS; ++k) {
                float oR = __shfl_down(rim[k], 1);
                float od = (k < ROWS - 1) ? rim[k + 1] : odn;
                int gi = gib + k;
                float gy = (gi < 511) ? od - rim[k] : 0.0f;
                float gx = gjlt ? oR - rim[k] : 0.0f;
                float inv = fast_rcp(fmaf(2.5f, fast_sqrt(fmaf(gy, gy, gx * gx)), 1.0f));
                rp0[k] = -0.25f * gy * inv;
                rp1[k] = -0.25f * gx * inv;
            }
        }
        s0 = 1;
    }

    for (int s = s0; s < NST; ++s) {
        bndP[tid] = rp0[ROWS - 1];
        __syncthreads();                 // B: bndP ready; also orders prior-stage bndO readers
        float pup0 = (w > 0) ? bndP[tid - 64] : 0.0f;
        if (interior) {
#pragma unroll
            for (int k = 0; k < ROWS; ++k) {
                float p1l = __shfl_up(rp1[k], 1);
                float pup = (k > 0) ? rp0[k - 1] : pup0;
                ro[k] = rim[k] - rp0[k] - rp1[k] + pup + p1l;
            }
            bndO[tid] = ro[0];
            __syncthreads();             // C
            float odn = (w < NW - 1) ? bndO[tid + 64] : 0.0f;
#pragma unroll
            for (int k = 0; k < ROWS; ++k) {
                float oR = __shfl_down(ro[k], 1);
                float od = (k < ROWS - 1) ? ro[k + 1] : odn;
                float gy = od - ro[k];
                float gx = oR - ro[k];
                float inv = fast_rcp(fmaf(2.5f, fast_sqrt(fmaf(gy, gy, gx * gx)), 1.0f));
                rp0[k] = (rp0[k] - 0.25f * gy) * inv;
                rp1[k] = (rp1[k] - 0.25f * gx) * inv;
            }
        } else {
#pragma unroll
            for (int k = 0; k < ROWS; ++k) {
                float p1l = __shfl_up(rp1[k], 1);
                float o = rim[k] - rp0[k] - rp1[k];
                float pup = (k > 0) ? rp0[k - 1] : pup0;
                int gi = gib + k;
                if (gi > 0) o += pup;
                if (gjpos) o += p1l;
                ro[k] = o;
            }
            bndO[tid] = ro[0];
            __syncthreads();             // C
            float odn = (w < NW - 1) ? bndO[tid + 64] : 0.0f;
#pragma unroll
            for (int k = 0; k < ROWS; ++k) {
                float oR = __shfl_down(ro[k], 1);
                float od = (k < ROWS - 1) ? ro[k + 1] : odn;
                int gi = gib + k;
                float gy = (gi < 511) ? od - ro[k] : 0.0f;
                float gx = gjlt ? oR - ro[k] : 0.0f;
                float inv = fast_rcp(fmaf(2.5f, fast_sqrt(fmaf(gy, gy, gx * gx)), 1.0f));
                rp0[k] = (rp0[k] - 0.25f * gy) * inv;
                rp1[k] = (rp1[k] - 0.25f * gx) * inv;
            }
        }
    }

    const bool cst = (lane >= HL && lane < HL + TC && gj < 512);
    if (LAST) {
        // den = img + div(p) on output tile
        bndP[tid] = rp0[ROWS - 1];
        __syncthreads();
        float pup0 = (w > 0) ? bndP[tid - 64] : 0.0f;
        float* D = pout + b * IMG_HW;
#pragma unroll
        for (int k = 0; k < ROWS; ++k) {
            float p1l = __shfl_up(rp1[k], 1);
            int gi = gib + k;
            int rk = w * ROWS + k;
            float o = rim[k] - rp0[k] - rp1[k];
            float pup = (k > 0) ? rp0[k - 1] : pup0;
            if (gi > 0) o += pup;
            if (gjpos) o += p1l;
            if (rk >= HL && rk < HL + TR && cst && gi < 512) D[(gi << 9) + gj] = o;
        }
    } else {
        float* Q0 = pout + b * IMG_HW;
        float* Q1 = pout + PSTR + b * IMG_HW;
#pragma unroll
        for (int k = 0; k < ROWS; ++k) {
            int rk = w * ROWS + k;
            int gi = gib + k;
            if (rk >= HL && rk < HL + TR && cst && gi < 512) {
                Q0[(gi << 9) + gj] = rp0[k];
                Q1[(gi << 9) + gj] = rp1[k];
            }
        }
    }
}

// ---------------- fused stem (3x3 s2 + SiLU) + dw1 (3x3 s2 + SiLU) + pw1 (1x1 32->64 + SiLU) ----
__global__ __launch_bounds__(256) void stem_dw1_pw1(const float* __restrict__ den,
                                                    const float* __restrict__ stemw,
                                                    const float* __restrict__ dw1w,
                                                    const float* __restrict__ pw1T,
                                                    float* __restrict__ out) {
    __shared__ float sDen[35 * 36];
    __shared__ float sStem[8 * 323];   // 8 ch x (17 rows x stride 19)
    __shared__ float sDw[32 * 64];     // dw1 out: [ic][px], px = dy*8+dx
    __shared__ float sW[576];
    __shared__ __align__(16) float sWp[2048];  // pw1T [ic][oc]
    const int tid = threadIdx.x;
    const int b = blockIdx.z;
    const int r0 = blockIdx.y * 32, c0 = blockIdx.x * 32;
    const float* D = den + b * IMG_HW;
    for (int e = tid; e < 576; e += 256) sW[e] = (e < 288) ? stemw[e] : dw1w[e - 288];
    for (int e = tid; e < 2048; e += 256) sWp[e] = pw1T[e];
    for (int e = tid; e < 35 * 35; e += 256) {
        int li = e / 35, lj = e % 35;
        int gi = r0 - 3 + li, gjj = c0 - 3 + lj;
        sDen[li * 36 + lj] = (gi >= 0 && gjj >= 0) ? D[(gi << 9) + gjj] : 0.0f;
    }
    __syncthreads();

    for (int g = 0; g < 4; ++g) {
        if (g) __syncthreads();
        // phase A: stem for channels 8g..8g+7 at 17x17 positions
        for (int e = tid; e < 2312; e += 256) {      // 289 pos x 8 ch
            int pos = e >> 3, cl = e & 7;
            int sy = pos / 17, sx = pos % 17;
            int c = 8 * g + cl;
            const float* wc = &sW[c * 9];
            const float* dbase = &sDen[(2 * sy) * 36 + 2 * sx];
            float a = 0.0f;
#pragma unroll
            for (int ky = 0; ky < 3; ++ky)
#pragma unroll
                for (int kx = 0; kx < 3; ++kx)
                    a = fmaf(wc[ky * 3 + kx], dbase[ky * 36 + kx], a);
            sStem[cl * 323 + sy * 19 + sx] = silu_f(a);
        }
        __syncthreads();
        // phase B: dw1 for channels 8g..8g+7 -> sDw
        for (int e = tid; e < 512; e += 256) {
            int cl = e >> 6, dy = (e >> 3) & 7, dx = e & 7;
            int c = 8 * g + cl;
            float acc = 0.0f;
#pragma unroll
            for (int ky = 0; ky < 3; ++ky)
#pragma unroll
                for (int kx = 0; kx < 3; ++kx) {
                    int sgy = (r0 >> 1) - 1 + 2 * dy + ky;
                    int sgx = (c0 >> 1) - 1 + 2 * dx + kx;
                    float v = (sgy >= 0 && sgx >= 0)
                        ? sStem[cl * 323 + (2 * dy + ky) * 19 + 2 * dx + kx] : 0.0f;
                    acc = fmaf(sW[288 + c * 9 + ky * 3 + kx], v, acc);
                }
            sDw[c * 64 + (dy << 3) + dx] = silu_f(acc);
        }
    }
    __syncthreads();

    // phase C: pw1 1x1 GEMM 32->64 + SiLU. px = lane, oc-quad = wave.
    const int px = tid & 63, oc0 = (tid >> 6) * 16;
    float acc[16];
#pragma unroll
    for (int j = 0; j < 16; ++j) acc[j] = 0.0f;
    for (int ic = 0; ic < 32; ++ic) {
        float v = sDw[ic * 64 + px];
        const float* wr = &sWp[ic * 64 + oc0];
#pragma unroll
        for (int q = 0; q < 4; ++q) {
            float4 w4 = *(const float4*)(wr + q * 4);
            acc[q * 4 + 0] = fmaf(v, w4.x, acc[q * 4 + 0]);
            acc[q * 4 + 1] = fmaf(v, w4.y, acc[q * 4 + 1]);
            acc[q * 4 + 2] = fmaf(v, w4.z, acc[q * 4 + 2]);
            acc[q * 4 + 3] = fmaf(v, w4.w, acc[q * 4 + 3]);
        }
    }
    const int gpos = ((r0 >> 2) + (px >> 3)) * 128 + (c0 >> 2) + (px & 7);
    float* ob = out + (size_t)b * 64 * 16384 + (size_t)oc0 * 16384 + gpos;
#pragma unroll
    for (int j = 0; j < 16; ++j) ob[(size_t)j * 16384] = silu_f(acc[j]);
}

// ---------------- depthwise 3x3 s2 pad1 + SiLU ----------------
template <int C, int HIN>
__global__ __launch_bounds__(256) void dw_kernel(const float* __restrict__ in,
                                                 const float* __restrict__ w,
                                                 float* __restrict__ out) {
    constexpr int HO = HIN / 2;
    int t = blockIdx.x * 256 + threadIdx.x;       // B*C*HO*HO
    int x = t % HO;
    int y = (t / HO) % HO;
    int c = (t / (HO * HO)) % C;
    int b = t / (HO * HO * C);
    const float* I = in + ((size_t)(b * C + c)) * (HIN * HIN);
    const float* wc = w + c * 9;
    int iy = 2 * y - 1, ix = 2 * x - 1;
    float acc = 0.0f;
#pragma unroll
    for (int ky = 0; ky < 3; ++ky)
#pragma unroll
        for (int kx = 0; kx < 3; ++kx) {
            int yy = iy + ky, xx = ix + kx;
            float vv = (yy >= 0 && xx >= 0) ? I[yy * HIN + xx] : 0.0f;
            acc = fmaf(wc[ky * 3 + kx], vv, acc);
        }
    out[t] = silu_f(acc);
}

// ---------------- depthwise 3x3 s2 + fused 2-way split-K reduce + SiLU input ----------------
template <int C, int HIN>
__global__ __launch_bounds__(256) void dw_reduce2_kernel(const float* __restrict__ part,
                                                         const float* __restrict__ w,
                                                         float* __restrict__ out) {
    constexpr int HO = HIN / 2;
    int t = blockIdx.x * 256 + threadIdx.x;
    int x = t % HO;
    int y = (t / HO) % HO;
    int c = (t / (HO * HO)) % C;
    int b = t / (HO * HO * C);
    const float* Ia = part + ((size_t)(b * C + c)) * (HIN * HIN);
    const float* Ib = Ia + (size_t)BATCH * C * HIN * HIN;
    const float* wc = w + c * 9;
    int iy = 2 * y - 1, ix = 2 * x - 1;
    float acc = 0.0f;
#pragma unroll
    for (int ky = 0; ky < 3; ++ky)
#pragma unroll
        for (int kx = 0; kx < 3; ++kx) {
            int yy = iy + ky, xx = ix + kx;
            float vv = 0.0f;
            if (yy >= 0 && xx >= 0) {
                int o = yy * HIN + xx;
                vv = silu_f(Ia[o] + Ib[o]);
            }
            acc = fmaf(wc[ky * 3 + kx], vv, acc);
        }
    out[t] = silu_f(acc);
}

// ---------------- pointwise 1x1 conv: double-buffered, split-K GEMM ----------------
template <int ICT, int NSIN, int NSPLIT, int OC, bool SILU>
__global__ __launch_bounds__(256) void pw_gemm(const float* __restrict__ in,
                                               const float* __restrict__ wT,
                                               float* __restrict__ out,
                                               int HW) {
    constexpr int KC = 32, TP = 64, TOC = 64, OPT = 4, PPT = 4;
    constexpr int KS = ICT / NSPLIT;
    constexpr int NC = KS / KC;
    constexpr int NOG = TOC / OPT;                // 16
    constexpr int PV4 = KC * TP / 4 / 256;        // 2 float4/thread (px)
    constexpr int WV4 = KC * TOC / 4 / 256;       // 2 float4/thread (w)
    static_assert(KS % KC == 0, "split");
    __shared__ __align__(16) float sPx[2][KC * TP];
    __shared__ __align__(16) float sW[2][KC * TOC];
    const int tid = threadIdx.x;
    const int zb = blockIdx.z;
    const int b = zb / NSPLIT, ks = zb % NSPLIT;
    const int p0 = blockIdx.x * TP;
    const int oc0 = blockIdx.y * TOC;
    const int ocg = tid % NOG, pxg = tid / NOG;   // pxg in [0,16)
    const size_t instride = (size_t)BATCH * ICT * HW;
    const float* gin0 = in + ((size_t)b * ICT + ks * KS) * HW + p0;
    const float* gw0  = wT + ((size_t)(ks * KS)) * OC + oc0;

    float4 rp[PV4], rw[WV4];
    auto load_chunk = [&](int cc) {
        const float* gin = gin0 + (size_t)cc * KC * HW;
#pragma unroll
        for (int i = 0; i < PV4; ++i) {
            int e = tid + i * 256;
            int row = e / (TP / 4), col = e % (TP / 4);
            const float* base = gin + (size_t)row * HW + col * 4;
            float4 a = *(const float4*)base;
#pragma unroll
            for (int s = 1; s < NSIN; ++s) {
                float4 t4 = *(const float4*)(base + (size_t)s * instride);
                a.x += t4.x; a.y += t4.y; a.z += t4.z; a.w += t4.w;
            }
            if (NSIN > 1) {
                a.x = silu_f(a.x); a.y = silu_f(a.y);
                a.z = silu_f(a.z); a.w = silu_f(a.w);
            }
            rp[i] = a;
        }
        const float* gw = gw0 + (size_t)cc * KC * OC;
#pragma unroll
        for (int i = 0; i < WV4; ++i) {
            int e = tid + i * 256;
            int row = e / (TOC / 4), col = e % (TOC / 4);
            rw[i] = *(const float4*)(gw + (size_t)row * OC + col * 4);
        }
    };
    auto store_chunk = [&](int buf) {
#pragma unroll
        for (int i = 0; i < PV4; ++i) ((float4*)sPx[buf])[tid + i * 256] = rp[i];
#pragma unroll
        for (int i = 0; i < WV4; ++i) ((float4*)sW[buf])[tid + i * 256] = rw[i];
    };

    float acc[OPT][PPT];
#pragma unroll
    for (int o = 0; o < OPT; ++o)
#pragma unroll
        for (int p = 0; p < PPT; ++p) acc[o][p] = 0.0f;

    load_chunk(0);
    store_chunk(0);
    __syncthreads();
    for (int cc = 0; cc < NC; ++cc) {
        if (cc + 1 < NC) load_chunk(cc + 1);
        const int buf = cc & 1;
#pragma unroll 4
        for (int k = 0; k < KC; ++k) {
            float4 pv = *(const float4*)&sPx[buf][k * TP + pxg * PPT];
            float4 wv = *(const float4*)&sW[buf][k * TOC + ocg * OPT];
            float w0 = wv.x, w1 = wv.y, w2 = wv.z, w3 = wv.w;
            acc[0][0] = fmaf(pv.x, w0, acc[0][0]);
            acc[0][1] = fmaf(pv.y, w0, acc[0][1]);
            acc[0][2] = fmaf(pv.z, w0, acc[0][2]);
            acc[0][3] = fmaf(pv.w, w0, acc[0][3]);
            acc[1][0] = fmaf(pv.x, w1, acc[1][0]);
            acc[1][1] = fmaf(pv.y, w1, acc[1][1]);
            acc[1][2] = fmaf(pv.z, w1, acc[1][2]);
            acc[1][3] = fmaf(pv.w, w1, acc[1][3]);
            acc[2][0] = fmaf(pv.x, w2, acc[2][0]);
            acc[2][1] = fmaf(pv.y, w2, acc[2][1]);
            acc[2][2] = fmaf(pv.z, w2, acc[2][2]);
            acc[2][3] = fmaf(pv.w, w2, acc[2][3]);
            acc[3][0] = fmaf(pv.x, w3, acc[3][0]);
            acc[3][1] = fmaf(pv.y, w3, acc[3][1]);
            acc[3][2] = fmaf(pv.z, w3, acc[3][2]);
            acc[3][3] = fmaf(pv.w, w3, acc[3][3]);
        }
        if (cc + 1 < NC) {
            store_chunk((cc + 1) & 1);
            __syncthreads();
        }
    }

    float* ob;
    if (NSPLIT == 1)
        ob = out + ((size_t)(b * OC + oc0 + ocg * OPT)) * HW + p0 + pxg * PPT;
    else
        ob = out + (((size_t)(ks * BATCH + b)) * OC + oc0 + ocg * OPT) * HW + p0 + pxg * PPT;
#pragma unroll
    for (int o = 0; o < OPT; ++o) {
        float4 r;
        r.x = SILU ? silu_f(acc[o][0]) : acc[o][0];
        r.y = SILU ? silu_f(acc[o][1]) : acc[o][1];
        r.z = SILU ? silu_f(acc[o][2]) : acc[o][2];
        r.w = SILU ? silu_f(acc[o][3]) : acc[o][3];
        *(float4*)(ob + (size_t)o * HW) = r;
    }
}

// ---------------- fused head-partial reduce (4-way) + SiLU + wcomb dot ----------------
__global__ __launch_bounds__(256) void tail_head(const float* __restrict__ part,
                                                 const float* __restrict__ wcomb,
                                                 const float* __restrict__ bcomb,
                                                 float* __restrict__ s) {
    __shared__ float red[256];
    constexpr size_t PS = (size_t)4 * 1280 * 256;  // per-split stride
    int b = blockIdx.x >> 4;                      // 64 blocks: 4 batch x 16 px-groups
    int px0 = (blockIdx.x & 15) << 4;
    int px = threadIdx.x & 15, kg = threadIdx.x >> 4;   // 16 k-groups of 80
    const float* h0 = part + (size_t)b * 1280 * 256 + px0 + px;
    float acc = 0.0f;
    int k0 = kg * 80;
    for (int k = k0; k < k0 + 80; ++k) {
        size_t off = (size_t)k * 256;
        float v = silu_f(h0[off] + h0[off + PS] + h0[off + 2 * PS] + h0[off + 3 * PS]);
        acc = fmaf(wcomb[k], v, acc);
    }
    red[threadIdx.x] = acc;
    __syncthreads();
    if (threadIdx.x < 16) {
        float a = bcomb[0];
#pragma unroll
        for (int g = 0; g < 16; ++g) a += red[g * 16 + threadIdx.x];
        s[b * 256 + px0 + threadIdx.x] = a;
    }
}

// ---------------- fused bilinear(16->512) + 2-level Haar LL + final bias ----------------
__global__ __launch_bounds__(256) void resize_haar(const float* __restrict__ s,
                                                   const float* __restrict__ finalb,
                                                   float* __restrict__ out) {
    int t = blockIdx.x * 256 + threadIdx.x;       // 4*128*128
    int c = t & 127, r = (t >> 7) & 127, b = t >> 14;
    const float* S = s + b * 256;
    float acc = 0.0f;
#pragma unroll
    for (int j = 0; j < 4; ++j) {
        float sy = ((4 * r + j) + 0.5f) * (1.0f / 32.0f) - 0.5f;
        int y0 = (int)floorf(sy);
        float fy = sy - (float)y0;
        int ya = y0 < 0 ? 0 : y0;
        int yb = (y0 + 1) > 15 ? 15 : (y0 + 1);
#pragma unroll
        for (int i = 0; i < 4; ++i) {
            float sx = ((4 * c + i) + 0.5f) * (1.0f / 32.0f) - 0.5f;
            int x0 = (int)floorf(sx);
            float fx = sx - (float)x0;
            int xa = x0 < 0 ? 0 : x0;
            int xb = (x0 + 1) > 15 ? 15 : (x0 + 1);
            float v0 = S[ya * 16 + xa] * (1.0f - fx) + S[ya * 16 + xb] * fx;
            float v1 = S[yb * 16 + xa] * (1.0f - fx) + S[yb * 16 + xb] * fx;
            acc += v0 * (1.0f - fy) + v1 * fy;
        }
    }
    out[t] = 0.25f * acc + finalb[0];
}

// ---------------- launch ----------------
extern "C" void kernel_launch(void* const* d_in, const int* in_sizes, int n_in,
                              void* d_out, int out_size, void* d_ws, size_t ws_size,
                              hipStream_t stream) {
    if (ws_size < WS_FLOATS * sizeof(float)) return;

    const float* img    = (const float*)d_in[0];
    const float* stem_w = (const float*)d_in[1];
    const float* dw1_w  = (const float*)d_in[2];
    const float* pw1_w  = (const float*)d_in[3];
    const float* dw2_w  = (const float*)d_in[4];
    const float* pw2_w  = (const float*)d_in[5];
    const float* dw3_w  = (const float*)d_in[6];
    const float* pw3_w  = (const float*)d_in[7];
    const float* dw4_w  = (const float*)d_in[8];
    const float* pw4_w  = (const float*)d_in[9];
    const float* head_w = (const float*)d_in[10];
    const float* proj_w = (const float*)d_in[11];
    const float* proj_b = (const float*)d_in[12];
    const float* final_w= (const float*)d_in[13];
    const float* final_b= (const float*)d_in[14];
    float* ws  = (float*)d_ws;
    float* out = (float*)d_out;

    // TV Chambolle: 20 iterations in 2 register-resident launches (10+10).
    // Launch 1 grid: 12x19x4 TV tiles (28-row valid) + 2 extra y-rows = 96 prep blocks.
    dim3 tvg1(12, 21, 4), tvg2(12, 19, 4);
    tv_reg<10, true,  false><<<tvg1, 512, 0, stream>>>(
        img, img, ws + O_PA,
        pw1_w, pw2_w, pw3_w, pw4_w, head_w, proj_w, proj_b, final_w, ws);
    tv_reg<10, false, true ><<<tvg2, 512, 0, stream>>>(
        img, ws + O_PA, ws + O_DEN,
        nullptr, nullptr, nullptr, nullptr, nullptr, nullptr, nullptr, nullptr, ws);

    // fused stem + dw1 + pw1 (den -> [B][64][128][128])
    stem_dw1_pw1<<<dim3(16, 16, 4), 256, 0, stream>>>(ws + O_DEN, stem_w, dw1_w,
                                                      ws + O_WT1, ws + O_A1);

    // backbone
    dw_kernel<64, 128><<<4096, 256, 0, stream>>>(ws + O_A1, dw2_w, ws + O_A2);
    pw_gemm<64, 1, 2, 128, false><<<dim3(64, 2, 8), 256, 0, stream>>>(ws + O_A2, ws + O_WT2, ws + O_PA, 4096);

    dw_reduce2_kernel<128, 64><<<2048, 256, 0, stream>>>(ws + O_PA, dw3_w, ws + O_A1);
    pw_gemm<128, 1, 2, 256, false><<<dim3(16, 4, 8), 256, 0, stream>>>(ws + O_A1, ws + O_WT3, ws + O_PA, 1024);

    dw_reduce2_kernel<256, 32><<<1024, 256, 0, stream>>>(ws + O_PA, dw4_w, ws + O_A2);
    pw_gemm<256, 1, 4, 512, false><<<dim3(4, 8, 16), 256, 0, stream>>>(ws + O_A2, ws + O_WT4, ws + O_PA, 256);

    // head 512->1280 @16x16: fused 4-way partial reduce+SiLU at staging, split-4 raw out -> A1
    pw_gemm<512, 4, 4, 1280, false><<<dim3(4, 20, 16), 256, 0, stream>>>(ws + O_PA, ws + O_WTH, ws + O_A1, 256);
    tail_head<<<64, 256, 0, stream>>>(ws + O_A1, ws + O_WCOMB, ws + O_BCOMB, ws + O_S);

    resize_haar<<<256, 256, 0, stream>>>(ws + O_S, final_b, out);
}

// Round 3
// 242.755 us; speedup vs baseline: 1.0436x; 1.0436x over previous
//
#include <hip/hip_runtime.h>
#include <math.h>

// ---------------- problem constants ----------------
constexpr int BATCH = 4;
constexpr int IMG_H = 512, IMG_W = 512;
constexpr int IMG_HW = IMG_H * IMG_W;          // 262144
constexpr int PSTR = BATCH * IMG_HW;           // p-plane stride 1048576

// ---------------- workspace layout (floats) ----------------
constexpr size_t O_PA   = 0;                       // p ping [2][4][512][512] (also split-K partial arena)
constexpr size_t O_PB   = O_PA + 2 * (size_t)PSTR; // p pong
constexpr size_t O_DEN  = O_PB + 2 * (size_t)PSTR; // denoised [4][512][512]
constexpr size_t O_A1   = O_DEN + (size_t)PSTR;    // arena1 (8388608 floats; also head-partial arena)
constexpr size_t O_A2   = O_A1 + 8388608;          // arena2 (2097152 floats)
constexpr size_t O_WT1  = O_A2 + 2097152;          // wT pw1  [32][64]
constexpr size_t O_WT2  = O_WT1 + 32 * 64;
constexpr size_t O_WT3  = O_WT2 + 64 * 128;
constexpr size_t O_WT4  = O_WT3 + 128 * 256;
constexpr size_t O_WTH  = O_WT4 + 256 * 512;
constexpr size_t O_WCOMB= O_WTH + 512 * 1280;      // [1280]
constexpr size_t O_BCOMB= O_WCOMB + 1280;          // [1]
constexpr size_t O_S    = O_BCOMB + 4;             // s field [4][16][16]
constexpr size_t WS_FLOATS = O_S + 1024;

// fast-math device helpers (1-ulp HW ops; validated absmax-neutral in R1)
__device__ __forceinline__ float fast_rcp(float x) { return __builtin_amdgcn_rcpf(x); }
__device__ __forceinline__ float fast_sqrt(float x) { return __builtin_amdgcn_sqrtf(x); }
__device__ __forceinline__ float silu_f(float x) {
    float e = __builtin_amdgcn_exp2f(-1.44269504088896f * x);
    return x * fast_rcp(1.0f + e);
}
__device__ __forceinline__ int clampi(int v, int lo, int hi) {
    return v < lo ? lo : (v > hi ? hi : v);
}

// ---------------- TV Chambolle: register-resident, shuffle-exchange ----------------
// R3: __launch_bounds__(512, 8) caps VGPR at 64 -> 4 blocks/CU (32 waves/CU,
// the HW cap). Grid is 912 blocks <= 1024 concurrent slots: each launch runs
// in ONE occupancy pass. Hand count of live set ~40-45 VGPR, so the cap
// should be spill-free. ROWS=6 (48-row span, 28 valid). prep merged into
// launch 1 as 96 extra blocks (by >= 19).
template <int NST, bool FIRST, bool LAST>
__global__ __launch_bounds__(512, 8) void tv_reg(const float* __restrict__ img,
                                                 const float* __restrict__ pin,
                                                 float* __restrict__ pout,
                                                 const float* __restrict__ pw1,
                                                 const float* __restrict__ pw2,
                                                 const float* __restrict__ pw3,
                                                 const float* __restrict__ pw4,
                                                 const float* __restrict__ headw,
                                                 const float* __restrict__ projw,
                                                 const float* __restrict__ projb,
                                                 const float* __restrict__ finalw,
                                                 float* __restrict__ ws) {
    constexpr int ROWS = 6, NW = 8, HL = 10, TC = 44, TR = 28;
    constexpr int TVY = 19;
    __shared__ float bndP[512], bndO[512];

    if constexpr (FIRST) {
        if (blockIdx.y >= TVY) {
            // ---- prep branch: 96 blocks, grid-stride over 814 work tiles ----
            __shared__ float tt[32][33];
            const int tid = threadIdx.x;
            const int pid = ((blockIdx.y - TVY) * 4 + blockIdx.z) * 12 + blockIdx.x; // [0,96)
            for (int t = pid; t < 814; t += 96) {
                const float* src = nullptr; float* dst = nullptr;
                int C = 0, R = 0, tr = 0, tc = 0;
                if (t < 640) {        // head: 1280(oc) x 512(ic) -> [512][1280]
                    src = headw; dst = ws + O_WTH; R = 1280; C = 512; tr = t >> 4; tc = t & 15;
                } else if (t < 768) { // pw4: 512 x 256 -> [256][512]
                    int e = t - 640; src = pw4; dst = ws + O_WT4; R = 512; C = 256; tr = e >> 3; tc = e & 7;
                } else if (t < 800) { // pw3: 256 x 128 -> [128][256]
                    int e = t - 768; src = pw3; dst = ws + O_WT3; R = 256; C = 128; tr = e >> 2; tc = e & 3;
                } else if (t < 808) { // pw2: 128 x 64 -> [64][128]
                    int e = t - 800; src = pw2; dst = ws + O_WT2; R = 128; C = 64; tr = e >> 1; tc = e & 1;
                } else if (t < 810) { // pw1: 64 x 32 -> [32][64]
                    int e = t - 808; src = pw1; dst = ws + O_WT1; R = 64; C = 32; tr = e; tc = 0;
                }
                const int tx = tid & 31, ty = tid >> 5;       // 32 x 16
                __syncthreads();                              // WAR on tt across t-iterations
                if (src) {
#pragma unroll
                    for (int j = 0; j < 2; ++j)
                        tt[ty + j * 16][tx] =
                            src[(size_t)(tr * 32 + ty + j * 16) * C + tc * 32 + tx];
                }
                __syncthreads();
                if (src) {
#pragma unroll
                    for (int j = 0; j < 2; ++j)
                        dst[(size_t)(tc * 32 + ty + j * 16) * R + tr * 32 + tx] =
                            tt[tx][ty + j * 16];
                } else if (t < 813) {                         // wcomb chunks of 512
                    int k = (t - 810) * 512 + tid;
                    if (k < 1280) {
                        float a = 0.0f;
                        for (int ch = 0; ch < 64; ++ch)
                            a = fmaf(finalw[ch], projw[ch * 1280 + k], a);
                        ws[O_WCOMB + k] = a;
                    }
                } else {                                      // t == 813: bcomb
                    if (tid == 0) {
                        float a = 0.0f;
                        for (int ch = 0; ch < 64; ++ch) a = fmaf(finalw[ch], projb[ch], a);
                        ws[O_BCOMB] = a;
                    }
                }
            }
            return;
        }
    }

    const int tid = threadIdx.x;
    const int lane = tid & 63, w = tid >> 6;
    const int b = blockIdx.z;
    const int r0 = blockIdx.y * TR, c0 = blockIdx.x * TC;
    const int gj = c0 - HL + lane;
    const int gjc = clampi(gj, 0, 511);
    const int gib = r0 - HL + w * ROWS;
    const float* I = img + b * IMG_HW;
    const bool interior = (r0 - HL >= 1) && (r0 + NW * ROWS - HL <= 511) &&
                          (c0 - HL >= 1) && (c0 + 64 - HL <= 511);

    float rim[ROWS], rp0[ROWS], rp1[ROWS], ro[ROWS];
#pragma unroll
    for (int k = 0; k < ROWS; ++k) {
        int gi = clampi(gib + k, 0, 511);
        rim[k] = I[(gi << 9) + gjc];
    }
    if (!FIRST) {
        const float* P0 = pin + b * IMG_HW;
        const float* P1 = pin + PSTR + b * IMG_HW;
#pragma unroll
        for (int k = 0; k < ROWS; ++k) {
            int gi = clampi(gib + k, 0, 511);
            rp0[k] = P0[(gi << 9) + gjc];
            rp1[k] = P1[(gi << 9) + gjc];
        }
    }
    const bool gjpos = (gj > 0), gjlt = (gj < 511);

    int s0 = 0;
    if (FIRST) {
        // stage 0 specialized: p == 0  =>  out-field == img
        bndO[tid] = rim[0];
        __syncthreads();
        float odn = (w < NW - 1) ? bndO[tid + 64] : 0.0f;
        if (interior) {
#pragma unroll
            for (int k = 0; k < ROWS; ++k) {
                float oR = __shfl_down(rim[k], 1);
                float od = (k < ROWS - 1) ? rim[k + 1] : odn;
                float gy = od - rim[k];
                float gx = oR - rim[k];
                float inv = fast_rcp(fmaf(2.5f, fast_sqrt(fmaf(gy, gy, gx * gx)), 1.0f));
                rp0[k] = -0.25f * gy * inv;
                rp1[k] = -0.25f * gx * inv;
            }
        } else {
#pragma unroll
            for (int k = 0; k < ROWS; ++k) {
                float oR = __shfl_down(rim[k], 1);
                float od = (k < ROWS - 1) ? rim[k + 1] : odn;
                int gi = gib + k;
                float gy = (gi < 511) ? od - rim[k] : 0.0f;
                float gx = gjlt ? oR - rim[k] : 0.0f;
                float inv = fast_rcp(fmaf(2.5f, fast_sqrt(fmaf(gy, gy, gx * gx)), 1.0f));
                rp0[k] = -0.25f * gy * inv;
                rp1[k] = -0.25f * gx * inv;
            }
        }
        s0 = 1;
    }

    for (int s = s0; s < NST; ++s) {
        bndP[tid] = rp0[ROWS - 1];
        __syncthreads();                 // B: bndP ready; also orders prior-stage bndO readers
        float pup0 = (w > 0) ? bndP[tid - 64] : 0.0f;
        if (interior) {
#pragma unroll
            for (int k = 0; k < ROWS; ++k) {
                float p1l = __shfl_up(rp1[k], 1);
                float pup = (k > 0) ? rp0[k - 1] : pup0;
                ro[k] = rim[k] - rp0[k] - rp1[k] + pup + p1l;
            }
            bndO[tid] = ro[0];
            __syncthreads();             // C
            float odn = (w < NW - 1) ? bndO[tid + 64] : 0.0f;
#pragma unroll
            for (int k = 0; k < ROWS; ++k) {
                float oR = __shfl_down(ro[k], 1);
                float od = (k < ROWS - 1) ? ro[k + 1] : odn;
                float gy = od - ro[k];
                float gx = oR - ro[k];
                float inv = fast_rcp(fmaf(2.5f, fast_sqrt(fmaf(gy, gy, gx * gx)), 1.0f));
                rp0[k] = (rp0[k] - 0.25f * gy) * inv;
                rp1[k] = (rp1[k] - 0.25f * gx) * inv;
            }
        } else {
#pragma unroll
            for (int k = 0; k < ROWS; ++k) {
                float p1l = __shfl_up(rp1[k], 1);
                float o = rim[k] - rp0[k] - rp1[k];
                float pup = (k > 0) ? rp0[k - 1] : pup0;
                int gi = gib + k;
                if (gi > 0) o += pup;
                if (gjpos) o += p1l;
                ro[k] = o;
            }
            bndO[tid] = ro[0];
            __syncthreads();             // C
            float odn = (w < NW - 1) ? bndO[tid + 64] : 0.0f;
#pragma unroll
            for (int k = 0; k < ROWS; ++k) {
                float oR = __shfl_down(ro[k], 1);
                float od = (k < ROWS - 1) ? ro[k + 1] : odn;
                int gi = gib + k;
                float gy = (gi < 511) ? od - ro[k] : 0.0f;
                float gx = gjlt ? oR - ro[k] : 0.0f;
                float inv = fast_rcp(fmaf(2.5f, fast_sqrt(fmaf(gy, gy, gx * gx)), 1.0f));
                rp0[k] = (rp0[k] - 0.25f * gy) * inv;
                rp1[k] = (rp1[k] - 0.25f * gx) * inv;
            }
        }
    }

    const bool cst = (lane >= HL && lane < HL + TC && gj < 512);
    if (LAST) {
        // den = img + div(p) on output tile
        bndP[tid] = rp0[ROWS - 1];
        __syncthreads();
        float pup0 = (w > 0) ? bndP[tid - 64] : 0.0f;
        float* D = pout + b * IMG_HW;
#pragma unroll
        for (int k = 0; k < ROWS; ++k) {
            float p1l = __shfl_up(rp1[k], 1);
            int gi = gib + k;
            int rk = w * ROWS + k;
            float o = rim[k] - rp0[k] - rp1[k];
            float pup = (k > 0) ? rp0[k - 1] : pup0;
            if (gi > 0) o += pup;
            if (gjpos) o += p1l;
            if (rk >= HL && rk < HL + TR && cst && gi < 512) D[(gi << 9) + gj] = o;
        }
    } else {
        float* Q0 = pout + b * IMG_HW;
        float* Q1 = pout + PSTR + b * IMG_HW;
#pragma unroll
        for (int k = 0; k < ROWS; ++k) {
            int rk = w * ROWS + k;
            int gi = gib + k;
            if (rk >= HL && rk < HL + TR && cst && gi < 512) {
                Q0[(gi << 9) + gj] = rp0[k];
                Q1[(gi << 9) + gj] = rp1[k];
            }
        }
    }
}

// ---------------- fused stem (3x3 s2 + SiLU) + dw1 (3x3 s2 + SiLU) + pw1 (1x1 32->64 + SiLU) ----
__global__ __launch_bounds__(256) void stem_dw1_pw1(const float* __restrict__ den,
                                                    const float* __restrict__ stemw,
                                                    const float* __restrict__ dw1w,
                                                    const float* __restrict__ pw1T,
                                                    float* __restrict__ out) {
    __shared__ float sDen[35 * 36];
    __shared__ float sStem[8 * 323];   // 8 ch x (17 rows x stride 19)
    __shared__ float sDw[32 * 64];     // dw1 out: [ic][px], px = dy*8+dx
    __shared__ float sW[576];
    __shared__ __align__(16) float sWp[2048];  // pw1T [ic][oc]
    const int tid = threadIdx.x;
    const int b = blockIdx.z;
    const int r0 = blockIdx.y * 32, c0 = blockIdx.x * 32;
    const float* D = den + b * IMG_HW;
    for (int e = tid; e < 576; e += 256) sW[e] = (e < 288) ? stemw[e] : dw1w[e - 288];
    for (int e = tid; e < 2048; e += 256) sWp[e] = pw1T[e];
    for (int e = tid; e < 35 * 35; e += 256) {
        int li = e / 35, lj = e % 35;
        int gi = r0 - 3 + li, gjj = c0 - 3 + lj;
        sDen[li * 36 + lj] = (gi >= 0 && gjj >= 0) ? D[(gi << 9) + gjj] : 0.0f;
    }
    __syncthreads();

    for (int g = 0; g < 4; ++g) {
        if (g) __syncthreads();
        // phase A: stem for channels 8g..8g+7 at 17x17 positions
        for (int e = tid; e < 2312; e += 256) {      // 289 pos x 8 ch
            int pos = e >> 3, cl = e & 7;
            int sy = pos / 17, sx = pos % 17;
            int c = 8 * g + cl;
            const float* wc = &sW[c * 9];
            const float* dbase = &sDen[(2 * sy) * 36 + 2 * sx];
            float a = 0.0f;
#pragma unroll
            for (int ky = 0; ky < 3; ++ky)
#pragma unroll
                for (int kx = 0; kx < 3; ++kx)
                    a = fmaf(wc[ky * 3 + kx], dbase[ky * 36 + kx], a);
            sStem[cl * 323 + sy * 19 + sx] = silu_f(a);
        }
        __syncthreads();
        // phase B: dw1 for channels 8g..8g+7 -> sDw
        for (int e = tid; e < 512; e += 256) {
            int cl = e >> 6, dy = (e >> 3) & 7, dx = e & 7;
            int c = 8 * g + cl;
            float acc = 0.0f;
#pragma unroll
            for (int ky = 0; ky < 3; ++ky)
#pragma unroll
                for (int kx = 0; kx < 3; ++kx) {
                    int sgy = (r0 >> 1) - 1 + 2 * dy + ky;
                    int sgx = (c0 >> 1) - 1 + 2 * dx + kx;
                    float v = (sgy >= 0 && sgx >= 0)
                        ? sStem[cl * 323 + (2 * dy + ky) * 19 + 2 * dx + kx] : 0.0f;
                    acc = fmaf(sW[288 + c * 9 + ky * 3 + kx], v, acc);
                }
            sDw[c * 64 + (dy << 3) + dx] = silu_f(acc);
        }
    }
    __syncthreads();

    // phase C: pw1 1x1 GEMM 32->64 + SiLU. px = lane, oc-quad = wave.
    const int px = tid & 63, oc0 = (tid >> 6) * 16;
    float acc[16];
#pragma unroll
    for (int j = 0; j < 16; ++j) acc[j] = 0.0f;
    for (int ic = 0; ic < 32; ++ic) {
        float v = sDw[ic * 64 + px];
        const float* wr = &sWp[ic * 64 + oc0];
#pragma unroll
        for (int q = 0; q < 4; ++q) {
            float4 w4 = *(const float4*)(wr + q * 4);
            acc[q * 4 + 0] = fmaf(v, w4.x, acc[q * 4 + 0]);
            acc[q * 4 + 1] = fmaf(v, w4.y, acc[q * 4 + 1]);
            acc[q * 4 + 2] = fmaf(v, w4.z, acc[q * 4 + 2]);
            acc[q * 4 + 3] = fmaf(v, w4.w, acc[q * 4 + 3]);
        }
    }
    const int gpos = ((r0 >> 2) + (px >> 3)) * 128 + (c0 >> 2) + (px & 7);
    float* ob = out + (size_t)b * 64 * 16384 + (size_t)oc0 * 16384 + gpos;
#pragma unroll
    for (int j = 0; j < 16; ++j) ob[(size_t)j * 16384] = silu_f(acc[j]);
}

// ---------------- depthwise 3x3 s2 pad1 + SiLU ----------------
template <int C, int HIN>
__global__ __launch_bounds__(256) void dw_kernel(const float* __restrict__ in,
                                                 const float* __restrict__ w,
                                                 float* __restrict__ out) {
    constexpr int HO = HIN / 2;
    int t = blockIdx.x * 256 + threadIdx.x;       // B*C*HO*HO
    int x = t % HO;
    int y = (t / HO) % HO;
    int c = (t / (HO * HO)) % C;
    int b = t / (HO * HO * C);
    const float* I = in + ((size_t)(b * C + c)) * (HIN * HIN);
    const float* wc = w + c * 9;
    int iy = 2 * y - 1, ix = 2 * x - 1;
    float acc = 0.0f;
#pragma unroll
    for (int ky = 0; ky < 3; ++ky)
#pragma unroll
        for (int kx = 0; kx < 3; ++kx) {
            int yy = iy + ky, xx = ix + kx;
            float vv = (yy >= 0 && xx >= 0) ? I[yy * HIN + xx] : 0.0f;
            acc = fmaf(wc[ky * 3 + kx], vv, acc);
        }
    out[t] = silu_f(acc);
}

// ---------------- depthwise 3x3 s2 + fused 2-way split-K reduce + SiLU input ----------------
template <int C, int HIN>
__global__ __launch_bounds__(256) void dw_reduce2_kernel(const float* __restrict__ part,
                                                         const float* __restrict__ w,
                                                         float* __restrict__ out) {
    constexpr int HO = HIN / 2;
    int t = blockIdx.x * 256 + threadIdx.x;
    int x = t % HO;
    int y = (t / HO) % HO;
    int c = (t / (HO * HO)) % C;
    int b = t / (HO * HO * C);
    const float* Ia = part + ((size_t)(b * C + c)) * (HIN * HIN);
    const float* Ib = Ia + (size_t)BATCH * C * HIN * HIN;
    const float* wc = w + c * 9;
    int iy = 2 * y - 1, ix = 2 * x - 1;
    float acc = 0.0f;
#pragma unroll
    for (int ky = 0; ky < 3; ++ky)
#pragma unroll
        for (int kx = 0; kx < 3; ++kx) {
            int yy = iy + ky, xx = ix + kx;
            float vv = 0.0f;
            if (yy >= 0 && xx >= 0) {
                int o = yy * HIN + xx;
                vv = silu_f(Ia[o] + Ib[o]);
            }
            acc = fmaf(wc[ky * 3 + kx], vv, acc);
        }
    out[t] = silu_f(acc);
}

// ---------------- pointwise 1x1 conv: double-buffered, split-K GEMM ----------------
template <int ICT, int NSIN, int NSPLIT, int OC, bool SILU>
__global__ __launch_bounds__(256) void pw_gemm(const float* __restrict__ in,
                                               const float* __restrict__ wT,
                                               float* __restrict__ out,
                                               int HW) {
    constexpr int KC = 32, TP = 64, TOC = 64, OPT = 4, PPT = 4;
    constexpr int KS = ICT / NSPLIT;
    constexpr int NC = KS / KC;
    constexpr int NOG = TOC / OPT;                // 16
    constexpr int PV4 = KC * TP / 4 / 256;        // 2 float4/thread (px)
    constexpr int WV4 = KC * TOC / 4 / 256;       // 2 float4/thread (w)
    static_assert(KS % KC == 0, "split");
    __shared__ __align__(16) float sPx[2][KC * TP];
    __shared__ __align__(16) float sW[2][KC * TOC];
    const int tid = threadIdx.x;
    const int zb = blockIdx.z;
    const int b = zb / NSPLIT, ks = zb % NSPLIT;
    const int p0 = blockIdx.x * TP;
    const int oc0 = blockIdx.y * TOC;
    const int ocg = tid % NOG, pxg = tid / NOG;   // pxg in [0,16)
    const size_t instride = (size_t)BATCH * ICT * HW;
    const float* gin0 = in + ((size_t)b * ICT + ks * KS) * HW + p0;
    const float* gw0  = wT + ((size_t)(ks * KS)) * OC + oc0;

    float4 rp[PV4], rw[WV4];
    auto load_chunk = [&](int cc) {
        const float* gin = gin0 + (size_t)cc * KC * HW;
#pragma unroll
        for (int i = 0; i < PV4; ++i) {
            int e = tid + i * 256;
            int row = e / (TP / 4), col = e % (TP / 4);
            const float* base = gin + (size_t)row * HW + col * 4;
            float4 a = *(const float4*)base;
#pragma unroll
            for (int s = 1; s < NSIN; ++s) {
                float4 t4 = *(const float4*)(base + (size_t)s * instride);
                a.x += t4.x; a.y += t4.y; a.z += t4.z; a.w += t4.w;
            }
            if (NSIN > 1) {
                a.x = silu_f(a.x); a.y = silu_f(a.y);
                a.z = silu_f(a.z); a.w = silu_f(a.w);
            }
            rp[i] = a;
        }
        const float* gw = gw0 + (size_t)cc * KC * OC;
#pragma unroll
        for (int i = 0; i < WV4; ++i) {
            int e = tid + i * 256;
            int row = e / (TOC / 4), col = e % (TOC / 4);
            rw[i] = *(const float4*)(gw + (size_t)row * OC + col * 4);
        }
    };
    auto store_chunk = [&](int buf) {
#pragma unroll
        for (int i = 0; i < PV4; ++i) ((float4*)sPx[buf])[tid + i * 256] = rp[i];
#pragma unroll
        for (int i = 0; i < WV4; ++i) ((float4*)sW[buf])[tid + i * 256] = rw[i];
    };

    float acc[OPT][PPT];
#pragma unroll
    for (int o = 0; o < OPT; ++o)
#pragma unroll
        for (int p = 0; p < PPT; ++p) acc[o][p] = 0.0f;

    load_chunk(0);
    store_chunk(0);
    __syncthreads();
    for (int cc = 0; cc < NC; ++cc) {
        if (cc + 1 < NC) load_chunk(cc + 1);
        const int buf = cc & 1;
#pragma unroll 4
        for (int k = 0; k < KC; ++k) {
            float4 pv = *(const float4*)&sPx[buf][k * TP + pxg * PPT];
            float4 wv = *(const float4*)&sW[buf][k * TOC + ocg * OPT];
            float w0 = wv.x, w1 = wv.y, w2 = wv.z, w3 = wv.w;
            acc[0][0] = fmaf(pv.x, w0, acc[0][0]);
            acc[0][1] = fmaf(pv.y, w0, acc[0][1]);
            acc[0][2] = fmaf(pv.z, w0, acc[0][2]);
            acc[0][3] = fmaf(pv.w, w0, acc[0][3]);
            acc[1][0] = fmaf(pv.x, w1, acc[1][0]);
            acc[1][1] = fmaf(pv.y, w1, acc[1][1]);
            acc[1][2] = fmaf(pv.z, w1, acc[1][2]);
            acc[1][3] = fmaf(pv.w, w1, acc[1][3]);
            acc[2][0] = fmaf(pv.x, w2, acc[2][0]);
            acc[2][1] = fmaf(pv.y, w2, acc[2][1]);
            acc[2][2] = fmaf(pv.z, w2, acc[2][2]);
            acc[2][3] = fmaf(pv.w, w2, acc[2][3]);
            acc[3][0] = fmaf(pv.x, w3, acc[3][0]);
            acc[3][1] = fmaf(pv.y, w3, acc[3][1]);
            acc[3][2] = fmaf(pv.z, w3, acc[3][2]);
            acc[3][3] = fmaf(pv.w, w3, acc[3][3]);
        }
        if (cc + 1 < NC) {
            store_chunk((cc + 1) & 1);
            __syncthreads();
        }
    }

    float* ob;
    if (NSPLIT == 1)
        ob = out + ((size_t)(b * OC + oc0 + ocg * OPT)) * HW + p0 + pxg * PPT;
    else
        ob = out + (((size_t)(ks * BATCH + b)) * OC + oc0 + ocg * OPT) * HW + p0 + pxg * PPT;
#pragma unroll
    for (int o = 0; o < OPT; ++o) {
        float4 r;
        r.x = SILU ? silu_f(acc[o][0]) : acc[o][0];
        r.y = SILU ? silu_f(acc[o][1]) : acc[o][1];
        r.z = SILU ? silu_f(acc[o][2]) : acc[o][2];
        r.w = SILU ? silu_f(acc[o][3]) : acc[o][3];
        *(float4*)(ob + (size_t)o * HW) = r;
    }
}

// ---------------- fused head-partial reduce (4-way) + SiLU + wcomb dot ----------------
__global__ __launch_bounds__(256) void tail_head(const float* __restrict__ part,
                                                 const float* __restrict__ wcomb,
                                                 const float* __restrict__ bcomb,
                                                 float* __restrict__ s) {
    __shared__ float red[256];
    constexpr size_t PS = (size_t)4 * 1280 * 256;  // per-split stride
    int b = blockIdx.x >> 4;                      // 64 blocks: 4 batch x 16 px-groups
    int px0 = (blockIdx.x & 15) << 4;
    int px = threadIdx.x & 15, kg = threadIdx.x >> 4;   // 16 k-groups of 80
    const float* h0 = part + (size_t)b * 1280 * 256 + px0 + px;
    float acc = 0.0f;
    int k0 = kg * 80;
    for (int k = k0; k < k0 + 80; ++k) {
        size_t off = (size_t)k * 256;
        float v = silu_f(h0[off] + h0[off + PS] + h0[off + 2 * PS] + h0[off + 3 * PS]);
        acc = fmaf(wcomb[k], v, acc);
    }
    red[threadIdx.x] = acc;
    __syncthreads();
    if (threadIdx.x < 16) {
        float a = bcomb[0];
#pragma unroll
        for (int g = 0; g < 16; ++g) a += red[g * 16 + threadIdx.x];
        s[b * 256 + px0 + threadIdx.x] = a;
    }
}

// ---------------- fused bilinear(16->512) + 2-level Haar LL + final bias ----------------
__global__ __launch_bounds__(256) void resize_haar(const float* __restrict__ s,
                                                   const float* __restrict__ finalb,
                                                   float* __restrict__ out) {
    int t = blockIdx.x * 256 + threadIdx.x;       // 4*128*128
    int c = t & 127, r = (t >> 7) & 127, b = t >> 14;
    const float* S = s + b * 256;
    float acc = 0.0f;
#pragma unroll
    for (int j = 0; j < 4; ++j) {
        float sy = ((4 * r + j) + 0.5f) * (1.0f / 32.0f) - 0.5f;
        int y0 = (int)floorf(sy);
        float fy = sy - (float)y0;
        int ya = y0 < 0 ? 0 : y0;
        int yb = (y0 + 1) > 15 ? 15 : (y0 + 1);
#pragma unroll
        for (int i = 0; i < 4; ++i) {
            float sx = ((4 * c + i) + 0.5f) * (1.0f / 32.0f) - 0.5f;
            int x0 = (int)floorf(sx);
            float fx = sx - (float)x0;
            int xa = x0 < 0 ? 0 : x0;
            int xb = (x0 + 1) > 15 ? 15 : (x0 + 1);
            float v0 = S[ya * 16 + xa] * (1.0f - fx) + S[ya * 16 + xb] * fx;
            float v1 = S[yb * 16 + xa] * (1.0f - fx) + S[yb * 16 + xb] * fx;
            acc += v0 * (1.0f - fy) + v1 * fy;
        }
    }
    out[t] = 0.25f * acc + finalb[0];
}

// ---------------- launch ----------------
extern "C" void kernel_launch(void* const* d_in, const int* in_sizes, int n_in,
                              void* d_out, int out_size, void* d_ws, size_t ws_size,
                              hipStream_t stream) {
    if (ws_size < WS_FLOATS * sizeof(float)) return;

    const float* img    = (const float*)d_in[0];
    const float* stem_w = (const float*)d_in[1];
    const float* dw1_w  = (const float*)d_in[2];
    const float* pw1_w  = (const float*)d_in[3];
    const float* dw2_w  = (const float*)d_in[4];
    const float* pw2_w  = (const float*)d_in[5];
    const float* dw3_w  = (const float*)d_in[6];
    const float* pw3_w  = (const float*)d_in[7];
    const float* dw4_w  = (const float*)d_in[8];
    const float* pw4_w  = (const float*)d_in[9];
    const float* head_w = (const float*)d_in[10];
    const float* proj_w = (const float*)d_in[11];
    const float* proj_b = (const float*)d_in[12];
    const float* final_w= (const float*)d_in[13];
    const float* final_b= (const float*)d_in[14];
    float* ws  = (float*)d_ws;
    float* out = (float*)d_out;

    // TV Chambolle: 20 iterations in 2 register-resident launches (10+10).
    // Launch 1 grid: 12x19x4 TV tiles (28-row valid) + 2 extra y-rows = 96 prep blocks.
    dim3 tvg1(12, 21, 4), tvg2(12, 19, 4);
    tv_reg<10, true,  false><<<tvg1, 512, 0, stream>>>(
        img, img, ws + O_PA,
        pw1_w, pw2_w, pw3_w, pw4_w, head_w, proj_w, proj_b, final_w, ws);
    tv_reg<10, false, true ><<<tvg2, 512, 0, stream>>>(
        img, ws + O_PA, ws + O_DEN,
        nullptr, nullptr, nullptr, nullptr, nullptr, nullptr, nullptr, nullptr, ws);

    // fused stem + dw1 + pw1 (den -> [B][64][128][128])
    stem_dw1_pw1<<<dim3(16, 16, 4), 256, 0, stream>>>(ws + O_DEN, stem_w, dw1_w,
                                                      ws + O_WT1, ws + O_A1);

    // backbone
    dw_kernel<64, 128><<<4096, 256, 0, stream>>>(ws + O_A1, dw2_w, ws + O_A2);
    pw_gemm<64, 1, 2, 128, false><<<dim3(64, 2, 8), 256, 0, stream>>>(ws + O_A2, ws + O_WT2, ws + O_PA, 4096);

    dw_reduce2_kernel<128, 64><<<2048, 256, 0, stream>>>(ws + O_PA, dw3_w, ws + O_A1);
    pw_gemm<128, 1, 2, 256, false><<<dim3(16, 4, 8), 256, 0, stream>>>(ws + O_A1, ws + O_WT3, ws + O_PA, 1024);

    dw_reduce2_kernel<256, 32><<<1024, 256, 0, stream>>>(ws + O_PA, dw4_w, ws + O_A2);
    pw_gemm<256, 1, 4, 512, false><<<dim3(4, 8, 16), 256, 0, stream>>>(ws + O_A2, ws + O_WT4, ws + O_PA, 256);

    // head 512->1280 @16x16: fused 4-way partial reduce+SiLU at staging, split-4 raw out -> A1
    pw_gemm<512, 4, 4, 1280, false><<<dim3(4, 20, 16), 256, 0, stream>>>(ws + O_PA, ws + O_WTH, ws + O_A1, 256);
    tail_head<<<64, 256, 0, stream>>>(ws + O_A1, ws + O_WCOMB, ws + O_BCOMB, ws + O_S);

    resize_haar<<<256, 256, 0, stream>>>(ws + O_S, final_b, out);
}

// Round 4
// 241.318 us; speedup vs baseline: 1.0498x; 1.0060x over previous
//
#include <hip/hip_runtime.h>
#include <math.h>

// ---------------- problem constants ----------------
constexpr int BATCH = 4;
constexpr int IMG_H = 512, IMG_W = 512;
constexpr int IMG_HW = IMG_H * IMG_W;          // 262144
constexpr int PSTR = BATCH * IMG_HW;           // p-plane stride 1048576

// ---------------- workspace layout (floats) ----------------
constexpr size_t O_PA   = 0;                       // p ping [2][4][512][512] (also split-K partial arena)
constexpr size_t O_PB   = O_PA + 2 * (size_t)PSTR; // p pong
constexpr size_t O_DEN  = O_PB + 2 * (size_t)PSTR; // denoised [4][512][512]
constexpr size_t O_A1   = O_DEN + (size_t)PSTR;    // arena1 (8388608 floats; also head-partial arena)
constexpr size_t O_A2   = O_A1 + 8388608;          // arena2 (2097152 floats)
constexpr size_t O_WT1  = O_A2 + 2097152;          // wT pw1  [32][64]
constexpr size_t O_WT2  = O_WT1 + 32 * 64;
constexpr size_t O_WT3  = O_WT2 + 64 * 128;
constexpr size_t O_WT4  = O_WT3 + 128 * 256;
constexpr size_t O_WTH  = O_WT4 + 256 * 512;
constexpr size_t O_WCOMB= O_WTH + 512 * 1280;      // [1280]
constexpr size_t O_BCOMB= O_WCOMB + 1280;          // [1]
constexpr size_t O_S    = O_BCOMB + 4;             // s field [4][16][16]
constexpr size_t WS_FLOATS = O_S + 1024;

// fast-math device helpers (1-ulp HW ops; validated absmax-neutral in R1)
__device__ __forceinline__ float fast_rcp(float x) { return __builtin_amdgcn_rcpf(x); }
__device__ __forceinline__ float fast_sqrt(float x) { return __builtin_amdgcn_sqrtf(x); }
__device__ __forceinline__ float silu_f(float x) {
    float e = __builtin_amdgcn_exp2f(-1.44269504088896f * x);
    return x * fast_rcp(1.0f + e);
}
__device__ __forceinline__ int clampi(int v, int lo, int hi) {
    return v < lo ? lo : (v > hi ? hi : v);
}

// ---------------- TV Chambolle: register-resident, shuffle-exchange ----------------
// R4: ONE barrier per stage (was 2). The circular dependency (wave w needs
// ro[0] of w+1, which needs rp0[5] of w) is broken by exporting the PARTIAL
// o-value partO = rim[0]-rp0[0]-rp1[0]+p1l pre-barrier; the consumer adds its
// own rp0[5] (the missing pup term): odn = bndO[w+1] + rp0[5]. WAR across
// stages handled by parity double-buffered bnd[2][512] (write to buffer s&1;
// stage s+1 writes the other buffer, and the barrier chain gives 2-stage
// separation before reuse). Boundary audit: unconditional pup in odn differs
// from the old gi>0-checked path ONLY at r0=0,w=0 (gi=-4), a fake clamped
// halo row that valid rows never read (top boundary handled by explicit
// gi>0 checks, not erosion). Valid outputs bit-identical.
// R3: __launch_bounds__(512,8) caps VGPR at 64 -> 4 blocks/CU, 1-pass grid.
template <int NST, bool FIRST, bool LAST>
__global__ __launch_bounds__(512, 8) void tv_reg(const float* __restrict__ img,
                                                 const float* __restrict__ pin,
                                                 float* __restrict__ pout,
                                                 const float* __restrict__ pw1,
                                                 const float* __restrict__ pw2,
                                                 const float* __restrict__ pw3,
                                                 const float* __restrict__ pw4,
                                                 const float* __restrict__ headw,
                                                 const float* __restrict__ projw,
                                                 const float* __restrict__ projb,
                                                 const float* __restrict__ finalw,
                                                 float* __restrict__ ws) {
    constexpr int ROWS = 6, NW = 8, HL = 10, TC = 44, TR = 28;
    constexpr int TVY = 19;
    __shared__ float bndP[2][512], bndO[2][512];

    if constexpr (FIRST) {
        if (blockIdx.y >= TVY) {
            // ---- prep branch: 96 blocks, grid-stride over 814 work tiles ----
            __shared__ float tt[32][33];
            const int tid = threadIdx.x;
            const int pid = ((blockIdx.y - TVY) * 4 + blockIdx.z) * 12 + blockIdx.x; // [0,96)
            for (int t = pid; t < 814; t += 96) {
                const float* src = nullptr; float* dst = nullptr;
                int C = 0, R = 0, tr = 0, tc = 0;
                if (t < 640) {        // head: 1280(oc) x 512(ic) -> [512][1280]
                    src = headw; dst = ws + O_WTH; R = 1280; C = 512; tr = t >> 4; tc = t & 15;
                } else if (t < 768) { // pw4: 512 x 256 -> [256][512]
                    int e = t - 640; src = pw4; dst = ws + O_WT4; R = 512; C = 256; tr = e >> 3; tc = e & 7;
                } else if (t < 800) { // pw3: 256 x 128 -> [128][256]
                    int e = t - 768; src = pw3; dst = ws + O_WT3; R = 256; C = 128; tr = e >> 2; tc = e & 3;
                } else if (t < 808) { // pw2: 128 x 64 -> [64][128]
                    int e = t - 800; src = pw2; dst = ws + O_WT2; R = 128; C = 64; tr = e >> 1; tc = e & 1;
                } else if (t < 810) { // pw1: 64 x 32 -> [32][64]
                    int e = t - 808; src = pw1; dst = ws + O_WT1; R = 64; C = 32; tr = e; tc = 0;
                }
                const int tx = tid & 31, ty = tid >> 5;       // 32 x 16
                __syncthreads();                              // WAR on tt across t-iterations
                if (src) {
#pragma unroll
                    for (int j = 0; j < 2; ++j)
                        tt[ty + j * 16][tx] =
                            src[(size_t)(tr * 32 + ty + j * 16) * C + tc * 32 + tx];
                }
                __syncthreads();
                if (src) {
#pragma unroll
                    for (int j = 0; j < 2; ++j)
                        dst[(size_t)(tc * 32 + ty + j * 16) * R + tr * 32 + tx] =
                            tt[tx][ty + j * 16];
                } else if (t < 813) {                         // wcomb chunks of 512
                    int k = (t - 810) * 512 + tid;
                    if (k < 1280) {
                        float a = 0.0f;
                        for (int ch = 0; ch < 64; ++ch)
                            a = fmaf(finalw[ch], projw[ch * 1280 + k], a);
                        ws[O_WCOMB + k] = a;
                    }
                } else {                                      // t == 813: bcomb
                    if (tid == 0) {
                        float a = 0.0f;
                        for (int ch = 0; ch < 64; ++ch) a = fmaf(finalw[ch], projb[ch], a);
                        ws[O_BCOMB] = a;
                    }
                }
            }
            return;
        }
    }

    const int tid = threadIdx.x;
    const int lane = tid & 63, w = tid >> 6;
    const int b = blockIdx.z;
    const int r0 = blockIdx.y * TR, c0 = blockIdx.x * TC;
    const int gj = c0 - HL + lane;
    const int gjc = clampi(gj, 0, 511);
    const int gib = r0 - HL + w * ROWS;
    const float* I = img + b * IMG_HW;
    const bool interior = (r0 - HL >= 1) && (r0 + NW * ROWS - HL <= 511) &&
                          (c0 - HL >= 1) && (c0 + 64 - HL <= 511);

    float rim[ROWS], rp0[ROWS], rp1[ROWS], ro[ROWS];
#pragma unroll
    for (int k = 0; k < ROWS; ++k) {
        int gi = clampi(gib + k, 0, 511);
        rim[k] = I[(gi << 9) + gjc];
    }
    if (!FIRST) {
        const float* P0 = pin + b * IMG_HW;
        const float* P1 = pin + PSTR + b * IMG_HW;
#pragma unroll
        for (int k = 0; k < ROWS; ++k) {
            int gi = clampi(gib + k, 0, 511);
            rp0[k] = P0[(gi << 9) + gjc];
            rp1[k] = P1[(gi << 9) + gjc];
        }
    }
    const bool gjpos = (gj > 0), gjlt = (gj < 511);

    int s0 = 0;
    if (FIRST) {
        // stage 0 specialized: p == 0  =>  out-field == img (uses parity-0 buffer;
        // stage 2's reuse of parity 0 is ordered by the stage-1 barrier chain)
        bndO[0][tid] = rim[0];
        __syncthreads();
        float odn = (w < NW - 1) ? bndO[0][tid + 64] : 0.0f;
        if (interior) {
#pragma unroll
            for (int k = 0; k < ROWS; ++k) {
                float oR = __shfl_down(rim[k], 1);
                float od = (k < ROWS - 1) ? rim[k + 1] : odn;
                float gy = od - rim[k];
                float gx = oR - rim[k];
                float inv = fast_rcp(fmaf(2.5f, fast_sqrt(fmaf(gy, gy, gx * gx)), 1.0f));
                rp0[k] = -0.25f * gy * inv;
                rp1[k] = -0.25f * gx * inv;
            }
        } else {
#pragma unroll
            for (int k = 0; k < ROWS; ++k) {
                float oR = __shfl_down(rim[k], 1);
                float od = (k < ROWS - 1) ? rim[k + 1] : odn;
                int gi = gib + k;
                float gy = (gi < 511) ? od - rim[k] : 0.0f;
                float gx = gjlt ? oR - rim[k] : 0.0f;
                float inv = fast_rcp(fmaf(2.5f, fast_sqrt(fmaf(gy, gy, gx * gx)), 1.0f));
                rp0[k] = -0.25f * gy * inv;
                rp1[k] = -0.25f * gx * inv;
            }
        }
        s0 = 1;
    }

    for (int s = s0; s < NST; ++s) {
        const int par = s & 1;
        // pre-barrier: export last-row p0 and PARTIAL first-row o (no pup term)
        float p1l0 = __shfl_up(rp1[0], 1);
        float partO = rim[0] - rp0[0] - rp1[0];
        if (interior) partO += p1l0;
        else if (gjpos) partO += p1l0;
        bndP[par][tid] = rp0[ROWS - 1];
        bndO[par][tid] = partO;
        __syncthreads();
        float pup0 = (w > 0) ? bndP[par][tid - 64] : 0.0f;
        // reconstruct down-neighbor's o: its missing pup term is OUR rp0[ROWS-1]
        float odn = (w < NW - 1) ? bndO[par][tid + 64] + rp0[ROWS - 1] : 0.0f;
        if (interior) {
            ro[0] = partO + pup0;
#pragma unroll
            for (int k = 1; k < ROWS; ++k) {
                float p1l = __shfl_up(rp1[k], 1);
                ro[k] = rim[k] - rp0[k] - rp1[k] + rp0[k - 1] + p1l;
            }
#pragma unroll
            for (int k = 0; k < ROWS; ++k) {
                float oR = __shfl_down(ro[k], 1);
                float od = (k < ROWS - 1) ? ro[k + 1] : odn;
                float gy = od - ro[k];
                float gx = oR - ro[k];
                float inv = fast_rcp(fmaf(2.5f, fast_sqrt(fmaf(gy, gy, gx * gx)), 1.0f));
                rp0[k] = (rp0[k] - 0.25f * gy) * inv;
                rp1[k] = (rp1[k] - 0.25f * gx) * inv;
            }
        } else {
            ro[0] = partO + ((gib > 0) ? pup0 : 0.0f);
#pragma unroll
            for (int k = 1; k < ROWS; ++k) {
                float p1l = __shfl_up(rp1[k], 1);
                float o = rim[k] - rp0[k] - rp1[k];
                if (gib + k > 0) o += rp0[k - 1];
                if (gjpos) o += p1l;
                ro[k] = o;
            }
#pragma unroll
            for (int k = 0; k < ROWS; ++k) {
                float oR = __shfl_down(ro[k], 1);
                float od = (k < ROWS - 1) ? ro[k + 1] : odn;
                int gi = gib + k;
                float gy = (gi < 511) ? od - ro[k] : 0.0f;
                float gx = gjlt ? oR - ro[k] : 0.0f;
                float inv = fast_rcp(fmaf(2.5f, fast_sqrt(fmaf(gy, gy, gx * gx)), 1.0f));
                rp0[k] = (rp0[k] - 0.25f * gy) * inv;
                rp1[k] = (rp1[k] - 0.25f * gx) * inv;
            }
        }
    }

    const bool cst = (lane >= HL && lane < HL + TC && gj < 512);
    if (LAST) {
        // den = img + div(p) on output tile (parity NST&1 buffer, single barrier)
        constexpr int epar = NST & 1;
        bndP[epar][tid] = rp0[ROWS - 1];
        __syncthreads();
        float pup0 = (w > 0) ? bndP[epar][tid - 64] : 0.0f;
        float* D = pout + b * IMG_HW;
#pragma unroll
        for (int k = 0; k < ROWS; ++k) {
            float p1l = __shfl_up(rp1[k], 1);
            int gi = gib + k;
            int rk = w * ROWS + k;
            float o = rim[k] - rp0[k] - rp1[k];
            float pup = (k > 0) ? rp0[k - 1] : pup0;
            if (gi > 0) o += pup;
            if (gjpos) o += p1l;
            if (rk >= HL && rk < HL + TR && cst && gi < 512) D[(gi << 9) + gj] = o;
        }
    } else {
        float* Q0 = pout + b * IMG_HW;
        float* Q1 = pout + PSTR + b * IMG_HW;
#pragma unroll
        for (int k = 0; k < ROWS; ++k) {
            int rk = w * ROWS + k;
            int gi = gib + k;
            if (rk >= HL && rk < HL + TR && cst && gi < 512) {
                Q0[(gi << 9) + gj] = rp0[k];
                Q1[(gi << 9) + gj] = rp1[k];
            }
        }
    }
}

// ---------------- fused stem (3x3 s2 + SiLU) + dw1 (3x3 s2 + SiLU) + pw1 (1x1 32->64 + SiLU) ----
__global__ __launch_bounds__(256) void stem_dw1_pw1(const float* __restrict__ den,
                                                    const float* __restrict__ stemw,
                                                    const float* __restrict__ dw1w,
                                                    const float* __restrict__ pw1T,
                                                    float* __restrict__ out) {
    __shared__ float sDen[35 * 36];
    __shared__ float sStem[8 * 323];   // 8 ch x (17 rows x stride 19)
    __shared__ float sDw[32 * 64];     // dw1 out: [ic][px], px = dy*8+dx
    __shared__ float sW[576];
    __shared__ __align__(16) float sWp[2048];  // pw1T [ic][oc]
    const int tid = threadIdx.x;
    const int b = blockIdx.z;
    const int r0 = blockIdx.y * 32, c0 = blockIdx.x * 32;
    const float* D = den + b * IMG_HW;
    for (int e = tid; e < 576; e += 256) sW[e] = (e < 288) ? stemw[e] : dw1w[e - 288];
    for (int e = tid; e < 2048; e += 256) sWp[e] = pw1T[e];
    for (int e = tid; e < 35 * 35; e += 256) {
        int li = e / 35, lj = e % 35;
        int gi = r0 - 3 + li, gjj = c0 - 3 + lj;
        sDen[li * 36 + lj] = (gi >= 0 && gjj >= 0) ? D[(gi << 9) + gjj] : 0.0f;
    }
    __syncthreads();

    for (int g = 0; g < 4; ++g) {
        if (g) __syncthreads();
        // phase A: stem for channels 8g..8g+7 at 17x17 positions
        for (int e = tid; e < 2312; e += 256) {      // 289 pos x 8 ch
            int pos = e >> 3, cl = e & 7;
            int sy = pos / 17, sx = pos % 17;
            int c = 8 * g + cl;
            const float* wc = &sW[c * 9];
            const float* dbase = &sDen[(2 * sy) * 36 + 2 * sx];
            float a = 0.0f;
#pragma unroll
            for (int ky = 0; ky < 3; ++ky)
#pragma unroll
                for (int kx = 0; kx < 3; ++kx)
                    a = fmaf(wc[ky * 3 + kx], dbase[ky * 36 + kx], a);
            sStem[cl * 323 + sy * 19 + sx] = silu_f(a);
        }
        __syncthreads();
        // phase B: dw1 for channels 8g..8g+7 -> sDw
        for (int e = tid; e < 512; e += 256) {
            int cl = e >> 6, dy = (e >> 3) & 7, dx = e & 7;
            int c = 8 * g + cl;
            float acc = 0.0f;
#pragma unroll
            for (int ky = 0; ky < 3; ++ky)
#pragma unroll
                for (int kx = 0; kx < 3; ++kx) {
                    int sgy = (r0 >> 1) - 1 + 2 * dy + ky;
                    int sgx = (c0 >> 1) - 1 + 2 * dx + kx;
                    float v = (sgy >= 0 && sgx >= 0)
                        ? sStem[cl * 323 + (2 * dy + ky) * 19 + 2 * dx + kx] : 0.0f;
                    acc = fmaf(sW[288 + c * 9 + ky * 3 + kx], v, acc);
                }
            sDw[c * 64 + (dy << 3) + dx] = silu_f(acc);
        }
    }
    __syncthreads();

    // phase C: pw1 1x1 GEMM 32->64 + SiLU. px = lane, oc-quad = wave.
    const int px = tid & 63, oc0 = (tid >> 6) * 16;
    float acc[16];
#pragma unroll
    for (int j = 0; j < 16; ++j) acc[j] = 0.0f;
    for (int ic = 0; ic < 32; ++ic) {
        float v = sDw[ic * 64 + px];
        const float* wr = &sWp[ic * 64 + oc0];
#pragma unroll
        for (int q = 0; q < 4; ++q) {
            float4 w4 = *(const float4*)(wr + q * 4);
            acc[q * 4 + 0] = fmaf(v, w4.x, acc[q * 4 + 0]);
            acc[q * 4 + 1] = fmaf(v, w4.y, acc[q * 4 + 1]);
            acc[q * 4 + 2] = fmaf(v, w4.z, acc[q * 4 + 2]);
            acc[q * 4 + 3] = fmaf(v, w4.w, acc[q * 4 + 3]);
        }
    }
    const int gpos = ((r0 >> 2) + (px >> 3)) * 128 + (c0 >> 2) + (px & 7);
    float* ob = out + (size_t)b * 64 * 16384 + (size_t)oc0 * 16384 + gpos;
#pragma unroll
    for (int j = 0; j < 16; ++j) ob[(size_t)j * 16384] = silu_f(acc[j]);
}

// ---------------- depthwise 3x3 s2 pad1 + SiLU ----------------
template <int C, int HIN>
__global__ __launch_bounds__(256) void dw_kernel(const float* __restrict__ in,
                                                 const float* __restrict__ w,
                                                 float* __restrict__ out) {
    constexpr int HO = HIN / 2;
    int t = blockIdx.x * 256 + threadIdx.x;       // B*C*HO*HO
    int x = t % HO;
    int y = (t / HO) % HO;
    int c = (t / (HO * HO)) % C;
    int b = t / (HO * HO * C);
    const float* I = in + ((size_t)(b * C + c)) * (HIN * HIN);
    const float* wc = w + c * 9;
    int iy = 2 * y - 1, ix = 2 * x - 1;
    float acc = 0.0f;
#pragma unroll
    for (int ky = 0; ky < 3; ++ky)
#pragma unroll
        for (int kx = 0; kx < 3; ++kx) {
            int yy = iy + ky, xx = ix + kx;
            float vv = (yy >= 0 && xx >= 0) ? I[yy * HIN + xx] : 0.0f;
            acc = fmaf(wc[ky * 3 + kx], vv, acc);
        }
    out[t] = silu_f(acc);
}

// ---------------- depthwise 3x3 s2 + fused 2-way split-K reduce + SiLU input ----------------
template <int C, int HIN>
__global__ __launch_bounds__(256) void dw_reduce2_kernel(const float* __restrict__ part,
                                                         const float* __restrict__ w,
                                                         float* __restrict__ out) {
    constexpr int HO = HIN / 2;
    int t = blockIdx.x * 256 + threadIdx.x;
    int x = t % HO;
    int y = (t / HO) % HO;
    int c = (t / (HO * HO)) % C;
    int b = t / (HO * HO * C);
    const float* Ia = part + ((size_t)(b * C + c)) * (HIN * HIN);
    const float* Ib = Ia + (size_t)BATCH * C * HIN * HIN;
    const float* wc = w + c * 9;
    int iy = 2 * y - 1, ix = 2 * x - 1;
    float acc = 0.0f;
#pragma unroll
    for (int ky = 0; ky < 3; ++ky)
#pragma unroll
        for (int kx = 0; kx < 3; ++kx) {
            int yy = iy + ky, xx = ix + kx;
            float vv = 0.0f;
            if (yy >= 0 && xx >= 0) {
                int o = yy * HIN + xx;
                vv = silu_f(Ia[o] + Ib[o]);
            }
            acc = fmaf(wc[ky * 3 + kx], vv, acc);
        }
    out[t] = silu_f(acc);
}

// ---------------- pointwise 1x1 conv: double-buffered, split-K GEMM ----------------
template <int ICT, int NSIN, int NSPLIT, int OC, bool SILU>
__global__ __launch_bounds__(256) void pw_gemm(const float* __restrict__ in,
                                               const float* __restrict__ wT,
                                               float* __restrict__ out,
                                               int HW) {
    constexpr int KC = 32, TP = 64, TOC = 64, OPT = 4, PPT = 4;
    constexpr int KS = ICT / NSPLIT;
    constexpr int NC = KS / KC;
    constexpr int NOG = TOC / OPT;                // 16
    constexpr int PV4 = KC * TP / 4 / 256;        // 2 float4/thread (px)
    constexpr int WV4 = KC * TOC / 4 / 256;       // 2 float4/thread (w)
    static_assert(KS % KC == 0, "split");
    __shared__ __align__(16) float sPx[2][KC * TP];
    __shared__ __align__(16) float sW[2][KC * TOC];
    const int tid = threadIdx.x;
    const int zb = blockIdx.z;
    const int b = zb / NSPLIT, ks = zb % NSPLIT;
    const int p0 = blockIdx.x * TP;
    const int oc0 = blockIdx.y * TOC;
    const int ocg = tid % NOG, pxg = tid / NOG;   // pxg in [0,16)
    const size_t instride = (size_t)BATCH * ICT * HW;
    const float* gin0 = in + ((size_t)b * ICT + ks * KS) * HW + p0;
    const float* gw0  = wT + ((size_t)(ks * KS)) * OC + oc0;

    float4 rp[PV4], rw[WV4];
    auto load_chunk = [&](int cc) {
        const float* gin = gin0 + (size_t)cc * KC * HW;
#pragma unroll
        for (int i = 0; i < PV4; ++i) {
            int e = tid + i * 256;
            int row = e / (TP / 4), col = e % (TP / 4);
            const float* base = gin + (size_t)row * HW + col * 4;
            float4 a = *(const float4*)base;
#pragma unroll
            for (int s = 1; s < NSIN; ++s) {
                float4 t4 = *(const float4*)(base + (size_t)s * instride);
                a.x += t4.x; a.y += t4.y; a.z += t4.z; a.w += t4.w;
            }
            if (NSIN > 1) {
                a.x = silu_f(a.x); a.y = silu_f(a.y);
                a.z = silu_f(a.z); a.w = silu_f(a.w);
            }
            rp[i] = a;
        }
        const float* gw = gw0 + (size_t)cc * KC * OC;
#pragma unroll
        for (int i = 0; i < WV4; ++i) {
            int e = tid + i * 256;
            int row = e / (TOC / 4), col = e % (TOC / 4);
            rw[i] = *(const float4*)(gw + (size_t)row * OC + col * 4);
        }
    };
    auto store_chunk = [&](int buf) {
#pragma unroll
        for (int i = 0; i < PV4; ++i) ((float4*)sPx[buf])[tid + i * 256] = rp[i];
#pragma unroll
        for (int i = 0; i < WV4; ++i) ((float4*)sW[buf])[tid + i * 256] = rw[i];
    };

    float acc[OPT][PPT];
#pragma unroll
    for (int o = 0; o < OPT; ++o)
#pragma unroll
        for (int p = 0; p < PPT; ++p) acc[o][p] = 0.0f;

    load_chunk(0);
    store_chunk(0);
    __syncthreads();
    for (int cc = 0; cc < NC; ++cc) {
        if (cc + 1 < NC) load_chunk(cc + 1);
        const int buf = cc & 1;
#pragma unroll 4
        for (int k = 0; k < KC; ++k) {
            float4 pv = *(const float4*)&sPx[buf][k * TP + pxg * PPT];
            float4 wv = *(const float4*)&sW[buf][k * TOC + ocg * OPT];
            float w0 = wv.x, w1 = wv.y, w2 = wv.z, w3 = wv.w;
            acc[0][0] = fmaf(pv.x, w0, acc[0][0]);
            acc[0][1] = fmaf(pv.y, w0, acc[0][1]);
            acc[0][2] = fmaf(pv.z, w0, acc[0][2]);
            acc[0][3] = fmaf(pv.w, w0, acc[0][3]);
            acc[1][0] = fmaf(pv.x, w1, acc[1][0]);
            acc[1][1] = fmaf(pv.y, w1, acc[1][1]);
            acc[1][2] = fmaf(pv.z, w1, acc[1][2]);
            acc[1][3] = fmaf(pv.w, w1, acc[1][3]);
            acc[2][0] = fmaf(pv.x, w2, acc[2][0]);
            acc[2][1] = fmaf(pv.y, w2, acc[2][1]);
            acc[2][2] = fmaf(pv.z, w2, acc[2][2]);
            acc[2][3] = fmaf(pv.w, w2, acc[2][3]);
            acc[3][0] = fmaf(pv.x, w3, acc[3][0]);
            acc[3][1] = fmaf(pv.y, w3, acc[3][1]);
            acc[3][2] = fmaf(pv.z, w3, acc[3][2]);
            acc[3][3] = fmaf(pv.w, w3, acc[3][3]);
        }
        if (cc + 1 < NC) {
            store_chunk((cc + 1) & 1);
            __syncthreads();
        }
    }

    float* ob;
    if (NSPLIT == 1)
        ob = out + ((size_t)(b * OC + oc0 + ocg * OPT)) * HW + p0 + pxg * PPT;
    else
        ob = out + (((size_t)(ks * BATCH + b)) * OC + oc0 + ocg * OPT) * HW + p0 + pxg * PPT;
#pragma unroll
    for (int o = 0; o < OPT; ++o) {
        float4 r;
        r.x = SILU ? silu_f(acc[o][0]) : acc[o][0];
        r.y = SILU ? silu_f(acc[o][1]) : acc[o][1];
        r.z = SILU ? silu_f(acc[o][2]) : acc[o][2];
        r.w = SILU ? silu_f(acc[o][3]) : acc[o][3];
        *(float4*)(ob + (size_t)o * HW) = r;
    }
}

// ---------------- fused head-partial reduce (4-way) + SiLU + wcomb dot ----------------
__global__ __launch_bounds__(256) void tail_head(const float* __restrict__ part,
                                                 const float* __restrict__ wcomb,
                                                 const float* __restrict__ bcomb,
                                                 float* __restrict__ s) {
    __shared__ float red[256];
    constexpr size_t PS = (size_t)4 * 1280 * 256;  // per-split stride
    int b = blockIdx.x >> 4;                      // 64 blocks: 4 batch x 16 px-groups
    int px0 = (blockIdx.x & 15) << 4;
    int px = threadIdx.x & 15, kg = threadIdx.x >> 4;   // 16 k-groups of 80
    const float* h0 = part + (size_t)b * 1280 * 256 + px0 + px;
    float acc = 0.0f;
    int k0 = kg * 80;
    for (int k = k0; k < k0 + 80; ++k) {
        size_t off = (size_t)k * 256;
        float v = silu_f(h0[off] + h0[off + PS] + h0[off + 2 * PS] + h0[off + 3 * PS]);
        acc = fmaf(wcomb[k], v, acc);
    }
    red[threadIdx.x] = acc;
    __syncthreads();
    if (threadIdx.x < 16) {
        float a = bcomb[0];
#pragma unroll
        for (int g = 0; g < 16; ++g) a += red[g * 16 + threadIdx.x];
        s[b * 256 + px0 + threadIdx.x] = a;
    }
}

// ---------------- fused bilinear(16->512) + 2-level Haar LL + final bias ----------------
__global__ __launch_bounds__(256) void resize_haar(const float* __restrict__ s,
                                                   const float* __restrict__ finalb,
                                                   float* __restrict__ out) {
    int t = blockIdx.x * 256 + threadIdx.x;       // 4*128*128
    int c = t & 127, r = (t >> 7) & 127, b = t >> 14;
    const float* S = s + b * 256;
    float acc = 0.0f;
#pragma unroll
    for (int j = 0; j < 4; ++j) {
        float sy = ((4 * r + j) + 0.5f) * (1.0f / 32.0f) - 0.5f;
        int y0 = (int)floorf(sy);
        float fy = sy - (float)y0;
        int ya = y0 < 0 ? 0 : y0;
        int yb = (y0 + 1) > 15 ? 15 : (y0 + 1);
#pragma unroll
        for (int i = 0; i < 4; ++i) {
            float sx = ((4 * c + i) + 0.5f) * (1.0f / 32.0f) - 0.5f;
            int x0 = (int)floorf(sx);
            float fx = sx - (float)x0;
            int xa = x0 < 0 ? 0 : x0;
            int xb = (x0 + 1) > 15 ? 15 : (x0 + 1);
            float v0 = S[ya * 16 + xa] * (1.0f - fx) + S[ya * 16 + xb] * fx;
            float v1 = S[yb * 16 + xa] * (1.0f - fx) + S[yb * 16 + xb] * fx;
            acc += v0 * (1.0f - fy) + v1 * fy;
        }
    }
    out[t] = 0.25f * acc + finalb[0];
}

// ---------------- launch ----------------
extern "C" void kernel_launch(void* const* d_in, const int* in_sizes, int n_in,
                              void* d_out, int out_size, void* d_ws, size_t ws_size,
                              hipStream_t stream) {
    if (ws_size < WS_FLOATS * sizeof(float)) return;

    const float* img    = (const float*)d_in[0];
    const float* stem_w = (const float*)d_in[1];
    const float* dw1_w  = (const float*)d_in[2];
    const float* pw1_w  = (const float*)d_in[3];
    const float* dw2_w  = (const float*)d_in[4];
    const float* pw2_w  = (const float*)d_in[5];
    const float* dw3_w  = (const float*)d_in[6];
    const float* pw3_w  = (const float*)d_in[7];
    const float* dw4_w  = (const float*)d_in[8];
    const float* pw4_w  = (const float*)d_in[9];
    const float* head_w = (const float*)d_in[10];
    const float* proj_w = (const float*)d_in[11];
    const float* proj_b = (const float*)d_in[12];
    const float* final_w= (const float*)d_in[13];
    const float* final_b= (const float*)d_in[14];
    float* ws  = (float*)d_ws;
    float* out = (float*)d_out;

    // TV Chambolle: 20 iterations in 2 register-resident launches (10+10).
    // Launch 1 grid: 12x19x4 TV tiles (28-row valid) + 2 extra y-rows = 96 prep blocks.
    dim3 tvg1(12, 21, 4), tvg2(12, 19, 4);
    tv_reg<10, true,  false><<<tvg1, 512, 0, stream>>>(
        img, img, ws + O_PA,
        pw1_w, pw2_w, pw3_w, pw4_w, head_w, proj_w, proj_b, final_w, ws);
    tv_reg<10, false, true ><<<tvg2, 512, 0, stream>>>(
        img, ws + O_PA, ws + O_DEN,
        nullptr, nullptr, nullptr, nullptr, nullptr, nullptr, nullptr, nullptr, ws);

    // fused stem + dw1 + pw1 (den -> [B][64][128][128])
    stem_dw1_pw1<<<dim3(16, 16, 4), 256, 0, stream>>>(ws + O_DEN, stem_w, dw1_w,
                                                      ws + O_WT1, ws + O_A1);

    // backbone
    dw_kernel<64, 128><<<4096, 256, 0, stream>>>(ws + O_A1, dw2_w, ws + O_A2);
    pw_gemm<64, 1, 2, 128, false><<<dim3(64, 2, 8), 256, 0, stream>>>(ws + O_A2, ws + O_WT2, ws + O_PA, 4096);

    dw_reduce2_kernel<128, 64><<<2048, 256, 0, stream>>>(ws + O_PA, dw3_w, ws + O_A1);
    pw_gemm<128, 1, 2, 256, false><<<dim3(16, 4, 8), 256, 0, stream>>>(ws + O_A1, ws + O_WT3, ws + O_PA, 1024);

    dw_reduce2_kernel<256, 32><<<1024, 256, 0, stream>>>(ws + O_PA, dw4_w, ws + O_A2);
    pw_gemm<256, 1, 4, 512, false><<<dim3(4, 8, 16), 256, 0, stream>>>(ws + O_A2, ws + O_WT4, ws + O_PA, 256);

    // head 512->1280 @16x16: fused 4-way partial reduce+SiLU at staging, split-4 raw out -> A1
    pw_gemm<512, 4, 4, 1280, false><<<dim3(4, 20, 16), 256, 0, stream>>>(ws + O_PA, ws + O_WTH, ws + O_A1, 256);
    tail_head<<<64, 256, 0, stream>>>(ws + O_A1, ws + O_WCOMB, ws + O_BCOMB, ws + O_S);

    resize_haar<<<256, 256, 0, stream>>>(ws + O_S, final_b, out);
}

// Round 5
// 239.270 us; speedup vs baseline: 1.0588x; 1.0086x over previous
//
#include <hip/hip_runtime.h>
#include <math.h>

// ---------------- problem constants ----------------
constexpr int BATCH = 4;
constexpr int IMG_H = 512, IMG_W = 512;
constexpr int IMG_HW = IMG_H * IMG_W;          // 262144
constexpr int PSTR = BATCH * IMG_HW;           // p-plane stride 1048576

// ---------------- workspace layout (floats) ----------------
constexpr size_t O_PA   = 0;                       // p ping [2][4][512][512] (also split-K partial arena)
constexpr size_t O_PB   = O_PA + 2 * (size_t)PSTR; // p pong
constexpr size_t O_DEN  = O_PB + 2 * (size_t)PSTR; // denoised [4][512][512]
constexpr size_t O_A1   = O_DEN + (size_t)PSTR;    // arena1 (8388608 floats; also head-partial field)
constexpr size_t O_A2   = O_A1 + 8388608;          // arena2 (2097152 floats)
constexpr size_t O_WT1  = O_A2 + 2097152;          // wT pw1  [32][64]
constexpr size_t O_WT2  = O_WT1 + 32 * 64;
constexpr size_t O_WT3  = O_WT2 + 64 * 128;
constexpr size_t O_WT4  = O_WT3 + 128 * 256;
constexpr size_t O_WTH  = O_WT4 + 256 * 512;
constexpr size_t O_WCOMB= O_WTH + 512 * 1280;      // [1280]
constexpr size_t O_BCOMB= O_WCOMB + 1280;          // [1]
constexpr size_t O_S    = O_BCOMB + 4;             // (unused now; kept for layout stability)
constexpr size_t WS_FLOATS = O_S + 1024;

// fast-math device helpers (1-ulp HW ops; validated absmax-neutral in R1)
__device__ __forceinline__ float fast_rcp(float x) { return __builtin_amdgcn_rcpf(x); }
__device__ __forceinline__ float fast_sqrt(float x) { return __builtin_amdgcn_sqrtf(x); }
__device__ __forceinline__ float silu_f(float x) {
    float e = __builtin_amdgcn_exp2f(-1.44269504088896f * x);
    return x * fast_rcp(1.0f + e);
}
__device__ __forceinline__ int clampi(int v, int lo, int hi) {
    return v < lo ? lo : (v > hi ? hi : v);
}

// ---------------- TV Chambolle: register-resident, shuffle-exchange ----------------
// (unchanged from R4: 1 barrier/stage, parity dbuf; R3: launch_bounds(512,8)
// -> 64 VGPR cap, 4 blocks/CU, single-occupancy-pass grid.)
template <int NST, bool FIRST, bool LAST>
__global__ __launch_bounds__(512, 8) void tv_reg(const float* __restrict__ img,
                                                 const float* __restrict__ pin,
                                                 float* __restrict__ pout,
                                                 const float* __restrict__ pw1,
                                                 const float* __restrict__ pw2,
                                                 const float* __restrict__ pw3,
                                                 const float* __restrict__ pw4,
                                                 const float* __restrict__ headw,
                                                 const float* __restrict__ projw,
                                                 const float* __restrict__ projb,
                                                 const float* __restrict__ finalw,
                                                 float* __restrict__ ws) {
    constexpr int ROWS = 6, NW = 8, HL = 10, TC = 44, TR = 28;
    constexpr int TVY = 19;
    __shared__ float bndP[2][512], bndO[2][512];

    if constexpr (FIRST) {
        if (blockIdx.y >= TVY) {
            // ---- prep branch: 96 blocks, grid-stride over 814 work tiles ----
            __shared__ float tt[32][33];
            const int tid = threadIdx.x;
            const int pid = ((blockIdx.y - TVY) * 4 + blockIdx.z) * 12 + blockIdx.x; // [0,96)
            for (int t = pid; t < 814; t += 96) {
                const float* src = nullptr; float* dst = nullptr;
                int C = 0, R = 0, tr = 0, tc = 0;
                if (t < 640) {        // head: 1280(oc) x 512(ic) -> [512][1280]
                    src = headw; dst = ws + O_WTH; R = 1280; C = 512; tr = t >> 4; tc = t & 15;
                } else if (t < 768) { // pw4: 512 x 256 -> [256][512]
                    int e = t - 640; src = pw4; dst = ws + O_WT4; R = 512; C = 256; tr = e >> 3; tc = e & 7;
                } else if (t < 800) { // pw3: 256 x 128 -> [128][256]
                    int e = t - 768; src = pw3; dst = ws + O_WT3; R = 256; C = 128; tr = e >> 2; tc = e & 3;
                } else if (t < 808) { // pw2: 128 x 64 -> [64][128]
                    int e = t - 800; src = pw2; dst = ws + O_WT2; R = 128; C = 64; tr = e >> 1; tc = e & 1;
                } else if (t < 810) { // pw1: 64 x 32 -> [32][64]
                    int e = t - 808; src = pw1; dst = ws + O_WT1; R = 64; C = 32; tr = e; tc = 0;
                }
                const int tx = tid & 31, ty = tid >> 5;       // 32 x 16
                __syncthreads();                              // WAR on tt across t-iterations
                if (src) {
#pragma unroll
                    for (int j = 0; j < 2; ++j)
                        tt[ty + j * 16][tx] =
                            src[(size_t)(tr * 32 + ty + j * 16) * C + tc * 32 + tx];
                }
                __syncthreads();
                if (src) {
#pragma unroll
                    for (int j = 0; j < 2; ++j)
                        dst[(size_t)(tc * 32 + ty + j * 16) * R + tr * 32 + tx] =
                            tt[tx][ty + j * 16];
                } else if (t < 813) {                         // wcomb chunks of 512
                    int k = (t - 810) * 512 + tid;
                    if (k < 1280) {
                        float a = 0.0f;
                        for (int ch = 0; ch < 64; ++ch)
                            a = fmaf(finalw[ch], projw[ch * 1280 + k], a);
                        ws[O_WCOMB + k] = a;
                    }
                } else {                                      // t == 813: bcomb
                    if (tid == 0) {
                        float a = 0.0f;
                        for (int ch = 0; ch < 64; ++ch) a = fmaf(finalw[ch], projb[ch], a);
                        ws[O_BCOMB] = a;
                    }
                }
            }
            return;
        }
    }

    const int tid = threadIdx.x;
    const int lane = tid & 63, w = tid >> 6;
    const int b = blockIdx.z;
    const int r0 = blockIdx.y * TR, c0 = blockIdx.x * TC;
    const int gj = c0 - HL + lane;
    const int gjc = clampi(gj, 0, 511);
    const int gib = r0 - HL + w * ROWS;
    const float* I = img + b * IMG_HW;
    const bool interior = (r0 - HL >= 1) && (r0 + NW * ROWS - HL <= 511) &&
                          (c0 - HL >= 1) && (c0 + 64 - HL <= 511);

    float rim[ROWS], rp0[ROWS], rp1[ROWS], ro[ROWS];
#pragma unroll
    for (int k = 0; k < ROWS; ++k) {
        int gi = clampi(gib + k, 0, 511);
        rim[k] = I[(gi << 9) + gjc];
    }
    if (!FIRST) {
        const float* P0 = pin + b * IMG_HW;
        const float* P1 = pin + PSTR + b * IMG_HW;
#pragma unroll
        for (int k = 0; k < ROWS; ++k) {
            int gi = clampi(gib + k, 0, 511);
            rp0[k] = P0[(gi << 9) + gjc];
            rp1[k] = P1[(gi << 9) + gjc];
        }
    }
    const bool gjpos = (gj > 0), gjlt = (gj < 511);

    int s0 = 0;
    if (FIRST) {
        // stage 0 specialized: p == 0  =>  out-field == img
        bndO[0][tid] = rim[0];
        __syncthreads();
        float odn = (w < NW - 1) ? bndO[0][tid + 64] : 0.0f;
        if (interior) {
#pragma unroll
            for (int k = 0; k < ROWS; ++k) {
                float oR = __shfl_down(rim[k], 1);
                float od = (k < ROWS - 1) ? rim[k + 1] : odn;
                float gy = od - rim[k];
                float gx = oR - rim[k];
                float inv = fast_rcp(fmaf(2.5f, fast_sqrt(fmaf(gy, gy, gx * gx)), 1.0f));
                rp0[k] = -0.25f * gy * inv;
                rp1[k] = -0.25f * gx * inv;
            }
        } else {
#pragma unroll
            for (int k = 0; k < ROWS; ++k) {
                float oR = __shfl_down(rim[k], 1);
                float od = (k < ROWS - 1) ? rim[k + 1] : odn;
                int gi = gib + k;
                float gy = (gi < 511) ? od - rim[k] : 0.0f;
                float gx = gjlt ? oR - rim[k] : 0.0f;
                float inv = fast_rcp(fmaf(2.5f, fast_sqrt(fmaf(gy, gy, gx * gx)), 1.0f));
                rp0[k] = -0.25f * gy * inv;
                rp1[k] = -0.25f * gx * inv;
            }
        }
        s0 = 1;
    }

    for (int s = s0; s < NST; ++s) {
        const int par = s & 1;
        float p1l0 = __shfl_up(rp1[0], 1);
        float partO = rim[0] - rp0[0] - rp1[0];
        if (interior) partO += p1l0;
        else if (gjpos) partO += p1l0;
        bndP[par][tid] = rp0[ROWS - 1];
        bndO[par][tid] = partO;
        __syncthreads();
        float pup0 = (w > 0) ? bndP[par][tid - 64] : 0.0f;
        float odn = (w < NW - 1) ? bndO[par][tid + 64] + rp0[ROWS - 1] : 0.0f;
        if (interior) {
            ro[0] = partO + pup0;
#pragma unroll
            for (int k = 1; k < ROWS; ++k) {
                float p1l = __shfl_up(rp1[k], 1);
                ro[k] = rim[k] - rp0[k] - rp1[k] + rp0[k - 1] + p1l;
            }
#pragma unroll
            for (int k = 0; k < ROWS; ++k) {
                float oR = __shfl_down(ro[k], 1);
                float od = (k < ROWS - 1) ? ro[k + 1] : odn;
                float gy = od - ro[k];
                float gx = oR - ro[k];
                float inv = fast_rcp(fmaf(2.5f, fast_sqrt(fmaf(gy, gy, gx * gx)), 1.0f));
                rp0[k] = (rp0[k] - 0.25f * gy) * inv;
                rp1[k] = (rp1[k] - 0.25f * gx) * inv;
            }
        } else {
            ro[0] = partO + ((gib > 0) ? pup0 : 0.0f);
#pragma unroll
            for (int k = 1; k < ROWS; ++k) {
                float p1l = __shfl_up(rp1[k], 1);
                float o = rim[k] - rp0[k] - rp1[k];
                if (gib + k > 0) o += rp0[k - 1];
                if (gjpos) o += p1l;
                ro[k] = o;
            }
#pragma unroll
            for (int k = 0; k < ROWS; ++k) {
                float oR = __shfl_down(ro[k], 1);
                float od = (k < ROWS - 1) ? ro[k + 1] : odn;
                int gi = gib + k;
                float gy = (gi < 511) ? od - ro[k] : 0.0f;
                float gx = gjlt ? oR - ro[k] : 0.0f;
                float inv = fast_rcp(fmaf(2.5f, fast_sqrt(fmaf(gy, gy, gx * gx)), 1.0f));
                rp0[k] = (rp0[k] - 0.25f * gy) * inv;
                rp1[k] = (rp1[k] - 0.25f * gx) * inv;
            }
        }
    }

    const bool cst = (lane >= HL && lane < HL + TC && gj < 512);
    if (LAST) {
        constexpr int epar = NST & 1;
        bndP[epar][tid] = rp0[ROWS - 1];
        __syncthreads();
        float pup0 = (w > 0) ? bndP[epar][tid - 64] : 0.0f;
        float* D = pout + b * IMG_HW;
#pragma unroll
        for (int k = 0; k < ROWS; ++k) {
            float p1l = __shfl_up(rp1[k], 1);
            int gi = gib + k;
            int rk = w * ROWS + k;
            float o = rim[k] - rp0[k] - rp1[k];
            float pup = (k > 0) ? rp0[k - 1] : pup0;
            if (gi > 0) o += pup;
            if (gjpos) o += p1l;
            if (rk >= HL && rk < HL + TR && cst && gi < 512) D[(gi << 9) + gj] = o;
        }
    } else {
        float* Q0 = pout + b * IMG_HW;
        float* Q1 = pout + PSTR + b * IMG_HW;
#pragma unroll
        for (int k = 0; k < ROWS; ++k) {
            int rk = w * ROWS + k;
            int gi = gib + k;
            if (rk >= HL && rk < HL + TR && cst && gi < 512) {
                Q0[(gi << 9) + gj] = rp0[k];
                Q1[(gi << 9) + gj] = rp1[k];
            }
        }
    }
}

// ---------------- fused stem (3x3 s2 + SiLU) + dw1 (3x3 s2 + SiLU) + pw1 (1x1 32->64 + SiLU) ----
__global__ __launch_bounds__(256) void stem_dw1_pw1(const float* __restrict__ den,
                                                    const float* __restrict__ stemw,
                                                    const float* __restrict__ dw1w,
                                                    const float* __restrict__ pw1T,
                                                    float* __restrict__ out) {
    __shared__ float sDen[35 * 36];
    __shared__ float sStem[8 * 323];   // 8 ch x (17 rows x stride 19)
    __shared__ float sDw[32 * 64];     // dw1 out: [ic][px], px = dy*8+dx
    __shared__ float sW[576];
    __shared__ __align__(16) float sWp[2048];  // pw1T [ic][oc]
    const int tid = threadIdx.x;
    const int b = blockIdx.z;
    const int r0 = blockIdx.y * 32, c0 = blockIdx.x * 32;
    const float* D = den + b * IMG_HW;
    for (int e = tid; e < 576; e += 256) sW[e] = (e < 288) ? stemw[e] : dw1w[e - 288];
    for (int e = tid; e < 2048; e += 256) sWp[e] = pw1T[e];
    for (int e = tid; e < 35 * 35; e += 256) {
        int li = e / 35, lj = e % 35;
        int gi = r0 - 3 + li, gjj = c0 - 3 + lj;
        sDen[li * 36 + lj] = (gi >= 0 && gjj >= 0) ? D[(gi << 9) + gjj] : 0.0f;
    }
    __syncthreads();

    for (int g = 0; g < 4; ++g) {
        if (g) __syncthreads();
        for (int e = tid; e < 2312; e += 256) {      // 289 pos x 8 ch
            int pos = e >> 3, cl = e & 7;
            int sy = pos / 17, sx = pos % 17;
            int c = 8 * g + cl;
            const float* wc = &sW[c * 9];
            const float* dbase = &sDen[(2 * sy) * 36 + 2 * sx];
            float a = 0.0f;
#pragma unroll
            for (int ky = 0; ky < 3; ++ky)
#pragma unroll
                for (int kx = 0; kx < 3; ++kx)
                    a = fmaf(wc[ky * 3 + kx], dbase[ky * 36 + kx], a);
            sStem[cl * 323 + sy * 19 + sx] = silu_f(a);
        }
        __syncthreads();
        for (int e = tid; e < 512; e += 256) {
            int cl = e >> 6, dy = (e >> 3) & 7, dx = e & 7;
            int c = 8 * g + cl;
            float acc = 0.0f;
#pragma unroll
            for (int ky = 0; ky < 3; ++ky)
#pragma unroll
                for (int kx = 0; kx < 3; ++kx) {
                    int sgy = (r0 >> 1) - 1 + 2 * dy + ky;
                    int sgx = (c0 >> 1) - 1 + 2 * dx + kx;
                    float v = (sgy >= 0 && sgx >= 0)
                        ? sStem[cl * 323 + (2 * dy + ky) * 19 + 2 * dx + kx] : 0.0f;
                    acc = fmaf(sW[288 + c * 9 + ky * 3 + kx], v, acc);
                }
            sDw[c * 64 + (dy << 3) + dx] = silu_f(acc);
        }
    }
    __syncthreads();

    const int px = tid & 63, oc0 = (tid >> 6) * 16;
    float acc[16];
#pragma unroll
    for (int j = 0; j < 16; ++j) acc[j] = 0.0f;
    for (int ic = 0; ic < 32; ++ic) {
        float v = sDw[ic * 64 + px];
        const float* wr = &sWp[ic * 64 + oc0];
#pragma unroll
        for (int q = 0; q < 4; ++q) {
            float4 w4 = *(const float4*)(wr + q * 4);
            acc[q * 4 + 0] = fmaf(v, w4.x, acc[q * 4 + 0]);
            acc[q * 4 + 1] = fmaf(v, w4.y, acc[q * 4 + 1]);
            acc[q * 4 + 2] = fmaf(v, w4.z, acc[q * 4 + 2]);
            acc[q * 4 + 3] = fmaf(v, w4.w, acc[q * 4 + 3]);
        }
    }
    const int gpos = ((r0 >> 2) + (px >> 3)) * 128 + (c0 >> 2) + (px & 7);
    float* ob = out + (size_t)b * 64 * 16384 + (size_t)oc0 * 16384 + gpos;
#pragma unroll
    for (int j = 0; j < 16; ++j) ob[(size_t)j * 16384] = silu_f(acc[j]);
}

// ---------------- depthwise 3x3 s2 pad1 + SiLU ----------------
template <int C, int HIN>
__global__ __launch_bounds__(256) void dw_kernel(const float* __restrict__ in,
                                                 const float* __restrict__ w,
                                                 float* __restrict__ out) {
    constexpr int HO = HIN / 2;
    int t = blockIdx.x * 256 + threadIdx.x;       // B*C*HO*HO
    int x = t % HO;
    int y = (t / HO) % HO;
    int c = (t / (HO * HO)) % C;
    int b = t / (HO * HO * C);
    const float* I = in + ((size_t)(b * C + c)) * (HIN * HIN);
    const float* wc = w + c * 9;
    int iy = 2 * y - 1, ix = 2 * x - 1;
    float acc = 0.0f;
#pragma unroll
    for (int ky = 0; ky < 3; ++ky)
#pragma unroll
        for (int kx = 0; kx < 3; ++kx) {
            int yy = iy + ky, xx = ix + kx;
            float vv = (yy >= 0 && xx >= 0) ? I[yy * HIN + xx] : 0.0f;
            acc = fmaf(wc[ky * 3 + kx], vv, acc);
        }
    out[t] = silu_f(acc);
}

// ---------------- depthwise 3x3 s2 + fused 2-way split-K reduce + SiLU input ----------------
template <int C, int HIN>
__global__ __launch_bounds__(256) void dw_reduce2_kernel(const float* __restrict__ part,
                                                         const float* __restrict__ w,
                                                         float* __restrict__ out) {
    constexpr int HO = HIN / 2;
    int t = blockIdx.x * 256 + threadIdx.x;
    int x = t % HO;
    int y = (t / HO) % HO;
    int c = (t / (HO * HO)) % C;
    int b = t / (HO * HO * C);
    const float* Ia = part + ((size_t)(b * C + c)) * (HIN * HIN);
    const float* Ib = Ia + (size_t)BATCH * C * HIN * HIN;
    const float* wc = w + c * 9;
    int iy = 2 * y - 1, ix = 2 * x - 1;
    float acc = 0.0f;
#pragma unroll
    for (int ky = 0; ky < 3; ++ky)
#pragma unroll
        for (int kx = 0; kx < 3; ++kx) {
            int yy = iy + ky, xx = ix + kx;
            float vv = 0.0f;
            if (yy >= 0 && xx >= 0) {
                int o = yy * HIN + xx;
                vv = silu_f(Ia[o] + Ib[o]);
            }
            acc = fmaf(wc[ky * 3 + kx], vv, acc);
        }
    out[t] = silu_f(acc);
}

// ---------------- pointwise 1x1 conv: double-buffered, split-K GEMM ----------------
template <int ICT, int NSIN, int NSPLIT, int OC, bool SILU>
__global__ __launch_bounds__(256) void pw_gemm(const float* __restrict__ in,
                                               const float* __restrict__ wT,
                                               float* __restrict__ out,
                                               int HW) {
    constexpr int KC = 32, TP = 64, TOC = 64, OPT = 4, PPT = 4;
    constexpr int KS = ICT / NSPLIT;
    constexpr int NC = KS / KC;
    constexpr int NOG = TOC / OPT;                // 16
    constexpr int PV4 = KC * TP / 4 / 256;        // 2 float4/thread (px)
    constexpr int WV4 = KC * TOC / 4 / 256;       // 2 float4/thread (w)
    static_assert(KS % KC == 0, "split");
    __shared__ __align__(16) float sPx[2][KC * TP];
    __shared__ __align__(16) float sW[2][KC * TOC];
    const int tid = threadIdx.x;
    const int zb = blockIdx.z;
    const int b = zb / NSPLIT, ks = zb % NSPLIT;
    const int p0 = blockIdx.x * TP;
    const int oc0 = blockIdx.y * TOC;
    const int ocg = tid % NOG, pxg = tid / NOG;   // pxg in [0,16)
    const size_t instride = (size_t)BATCH * ICT * HW;
    const float* gin0 = in + ((size_t)b * ICT + ks * KS) * HW + p0;
    const float* gw0  = wT + ((size_t)(ks * KS)) * OC + oc0;

    float4 rp[PV4], rw[WV4];
    auto load_chunk = [&](int cc) {
        const float* gin = gin0 + (size_t)cc * KC * HW;
#pragma unroll
        for (int i = 0; i < PV4; ++i) {
            int e = tid + i * 256;
            int row = e / (TP / 4), col = e % (TP / 4);
            const float* base = gin + (size_t)row * HW + col * 4;
            float4 a = *(const float4*)base;
#pragma unroll
            for (int s = 1; s < NSIN; ++s) {
                float4 t4 = *(const float4*)(base + (size_t)s * instride);
                a.x += t4.x; a.y += t4.y; a.z += t4.z; a.w += t4.w;
            }
            if (NSIN > 1) {
                a.x = silu_f(a.x); a.y = silu_f(a.y);
                a.z = silu_f(a.z); a.w = silu_f(a.w);
            }
            rp[i] = a;
        }
        const float* gw = gw0 + (size_t)cc * KC * OC;
#pragma unroll
        for (int i = 0; i < WV4; ++i) {
            int e = tid + i * 256;
            int row = e / (TOC / 4), col = e % (TOC / 4);
            rw[i] = *(const float4*)(gw + (size_t)row * OC + col * 4);
        }
    };
    auto store_chunk = [&](int buf) {
#pragma unroll
        for (int i = 0; i < PV4; ++i) ((float4*)sPx[buf])[tid + i * 256] = rp[i];
#pragma unroll
        for (int i = 0; i < WV4; ++i) ((float4*)sW[buf])[tid + i * 256] = rw[i];
    };

    float acc[OPT][PPT];
#pragma unroll
    for (int o = 0; o < OPT; ++o)
#pragma unroll
        for (int p = 0; p < PPT; ++p) acc[o][p] = 0.0f;

    load_chunk(0);
    store_chunk(0);
    __syncthreads();
    for (int cc = 0; cc < NC; ++cc) {
        if (cc + 1 < NC) load_chunk(cc + 1);
        const int buf = cc & 1;
#pragma unroll 4
        for (int k = 0; k < KC; ++k) {
            float4 pv = *(const float4*)&sPx[buf][k * TP + pxg * PPT];
            float4 wv = *(const float4*)&sW[buf][k * TOC + ocg * OPT];
            float w0 = wv.x, w1 = wv.y, w2 = wv.z, w3 = wv.w;
            acc[0][0] = fmaf(pv.x, w0, acc[0][0]);
            acc[0][1] = fmaf(pv.y, w0, acc[0][1]);
            acc[0][2] = fmaf(pv.z, w0, acc[0][2]);
            acc[0][3] = fmaf(pv.w, w0, acc[0][3]);
            acc[1][0] = fmaf(pv.x, w1, acc[1][0]);
            acc[1][1] = fmaf(pv.y, w1, acc[1][1]);
            acc[1][2] = fmaf(pv.z, w1, acc[1][2]);
            acc[1][3] = fmaf(pv.w, w1, acc[1][3]);
            acc[2][0] = fmaf(pv.x, w2, acc[2][0]);
            acc[2][1] = fmaf(pv.y, w2, acc[2][1]);
            acc[2][2] = fmaf(pv.z, w2, acc[2][2]);
            acc[2][3] = fmaf(pv.w, w2, acc[2][3]);
            acc[3][0] = fmaf(pv.x, w3, acc[3][0]);
            acc[3][1] = fmaf(pv.y, w3, acc[3][1]);
            acc[3][2] = fmaf(pv.z, w3, acc[3][2]);
            acc[3][3] = fmaf(pv.w, w3, acc[3][3]);
        }
        if (cc + 1 < NC) {
            store_chunk((cc + 1) & 1);
            __syncthreads();
        }
    }

    float* ob;
    if (NSPLIT == 1)
        ob = out + ((size_t)(b * OC + oc0 + ocg * OPT)) * HW + p0 + pxg * PPT;
    else
        ob = out + (((size_t)(ks * BATCH + b)) * OC + oc0 + ocg * OPT) * HW + p0 + pxg * PPT;
#pragma unroll
    for (int o = 0; o < OPT; ++o) {
        float4 r;
        r.x = SILU ? silu_f(acc[o][0]) : acc[o][0];
        r.y = SILU ? silu_f(acc[o][1]) : acc[o][1];
        r.z = SILU ? silu_f(acc[o][2]) : acc[o][2];
        r.w = SILU ? silu_f(acc[o][3]) : acc[o][3];
        *(float4*)(ob + (size_t)o * HW) = r;
    }
}

// ---------------- head GEMM 512->1280, full-K, fused silu+wcomb-dot epilogue ----------------
// R5: replaces pw_gemm<512,4,4,1280> (20 MB split-K out) + tail_head (20 MB in).
// Staging: sum pw4's 4 split partials + SiLU (same as before). Full K=512 per
// block (NC=16 chunks), 64-oc x 32-px tile, grid (8,20,4)=640 blocks.
// Epilogue: partial[ocblk][b][px] = sum_oc wcomb[oc]*silu(head), 20 KB field.
__global__ __launch_bounds__(256) void head_fused(const float* __restrict__ in,
                                                  const float* __restrict__ wT,
                                                  const float* __restrict__ wcomb,
                                                  float* __restrict__ partial) {
    constexpr int ICT = 512, KC = 32, TP = 32, TOC = 64, OC = 1280, HW = 256;
    constexpr int NC = ICT / KC;                  // 16
    __shared__ __align__(16) float sPx[2][KC * TP];   // 4 KB x2
    __shared__ __align__(16) float sW[2][KC * TOC];   // 8 KB x2
    __shared__ float red[512];
    const int tid = threadIdx.x;
    const int b = blockIdx.z;
    const int p0 = blockIdx.x * TP;
    const int oc0 = blockIdx.y * TOC;
    const int ocg = tid & 15, pxg = tid >> 4;     // ocg in [0,16), pxg in [0,16)
    const size_t instride = (size_t)BATCH * ICT * HW;   // pw4 split stride
    const float* gin0 = in + (size_t)b * ICT * HW + p0;

    float4 rp, rw[2];
    auto load_chunk = [&](int cc) {
        const float* gin = gin0 + (size_t)cc * KC * HW;
        {
            int row = tid >> 3, col = tid & 7;    // 32 rows x 8 float4
            const float* base = gin + (size_t)row * HW + col * 4;
            float4 a = *(const float4*)base;
#pragma unroll
            for (int s = 1; s < 4; ++s) {
                float4 t4 = *(const float4*)(base + (size_t)s * instride);
                a.x += t4.x; a.y += t4.y; a.z += t4.z; a.w += t4.w;
            }
            a.x = silu_f(a.x); a.y = silu_f(a.y);
            a.z = silu_f(a.z); a.w = silu_f(a.w);
            rp = a;
        }
        const float* gw = wT + ((size_t)cc * KC) * OC + oc0;
#pragma unroll
        for (int i = 0; i < 2; ++i) {
            int e = tid + i * 256;
            int row = e >> 4, col = e & 15;       // 32 rows x 16 float4
            rw[i] = *(const float4*)(gw + (size_t)row * OC + col * 4);
        }
    };
    auto store_chunk = [&](int buf) {
        ((float4*)sPx[buf])[tid] = rp;
#pragma unroll
        for (int i = 0; i < 2; ++i) ((float4*)sW[buf])[tid + i * 256] = rw[i];
    };

    float acc[4][2];
#pragma unroll
    for (int o = 0; o < 4; ++o) { acc[o][0] = 0.0f; acc[o][1] = 0.0f; }

    load_chunk(0);
    store_chunk(0);
    __syncthreads();
    for (int cc = 0; cc < NC; ++cc) {
        if (cc + 1 < NC) load_chunk(cc + 1);
        const int buf = cc & 1;
#pragma unroll 4
        for (int k = 0; k < KC; ++k) {
            float2 pv = *(const float2*)&sPx[buf][k * TP + pxg * 2];
            float4 wv = *(const float4*)&sW[buf][k * TOC + ocg * 4];
            acc[0][0] = fmaf(pv.x, wv.x, acc[0][0]);
            acc[0][1] = fmaf(pv.y, wv.x, acc[0][1]);
            acc[1][0] = fmaf(pv.x, wv.y, acc[1][0]);
            acc[1][1] = fmaf(pv.y, wv.y, acc[1][1]);
            acc[2][0] = fmaf(pv.x, wv.z, acc[2][0]);
            acc[2][1] = fmaf(pv.y, wv.z, acc[2][1]);
            acc[3][0] = fmaf(pv.x, wv.w, acc[3][0]);
            acc[3][1] = fmaf(pv.y, wv.w, acc[3][1]);
        }
        if (cc + 1 < NC) {
            store_chunk((cc + 1) & 1);
            __syncthreads();
        }
    }

    // epilogue: silu + wcomb dot over this thread's 4 ocs, reduce over ocg
    float4 wc4 = *(const float4*)(wcomb + oc0 + ocg * 4);
#pragma unroll
    for (int p = 0; p < 2; ++p) {
        float v = wc4.x * silu_f(acc[0][p]);
        v = fmaf(wc4.y, silu_f(acc[1][p]), v);
        v = fmaf(wc4.z, silu_f(acc[2][p]), v);
        v = fmaf(wc4.w, silu_f(acc[3][p]), v);
        red[(pxg * 2 + p) * 16 + ocg] = v;
    }
    __syncthreads();
    if (tid < 32) {
        float a = 0.0f;
#pragma unroll
        for (int g = 0; g < 16; ++g) a += red[tid * 16 + g];
        partial[((size_t)blockIdx.y * 4 + b) * 256 + p0 + tid] = a;
    }
}

// ---------------- fused 20-way partial reduce + bilinear(16->512) + 2-level Haar LL + bias ----
__global__ __launch_bounds__(256) void resize_haar(const float* __restrict__ partial,
                                                   const float* __restrict__ bcomb,
                                                   const float* __restrict__ finalb,
                                                   float* __restrict__ out) {
    __shared__ float sS[256];
    int t = blockIdx.x * 256 + threadIdx.x;       // 4*128*128; each block = one b
    int c = t & 127, r = (t >> 7) & 127, b = t >> 14;
    {   // s[b][px] = bcomb + sum over 20 oc-block partials
        float a = bcomb[0];
        const float* P = partial + (size_t)b * 256 + threadIdx.x;
        for (int y = 0; y < 20; ++y) a += P[(size_t)y * 1024];
        sS[threadIdx.x] = a;
    }
    __syncthreads();
    const float* S = sS;
    float acc = 0.0f;
#pragma unroll
    for (int j = 0; j < 4; ++j) {
        float sy = ((4 * r + j) + 0.5f) * (1.0f / 32.0f) - 0.5f;
        int y0 = (int)floorf(sy);
        float fy = sy - (float)y0;
        int ya = y0 < 0 ? 0 : y0;
        int yb = (y0 + 1) > 15 ? 15 : (y0 + 1);
#pragma unroll
        for (int i = 0; i < 4; ++i) {
            float sx = ((4 * c + i) + 0.5f) * (1.0f / 32.0f) - 0.5f;
            int x0 = (int)floorf(sx);
            float fx = sx - (float)x0;
            int xa = x0 < 0 ? 0 : x0;
            int xb = (x0 + 1) > 15 ? 15 : (x0 + 1);
            float v0 = S[ya * 16 + xa] * (1.0f - fx) + S[ya * 16 + xb] * fx;
            float v1 = S[yb * 16 + xa] * (1.0f - fx) + S[yb * 16 + xb] * fx;
            acc += v0 * (1.0f - fy) + v1 * fy;
        }
    }
    out[t] = 0.25f * acc + finalb[0];
}

// ---------------- launch ----------------
extern "C" void kernel_launch(void* const* d_in, const int* in_sizes, int n_in,
                              void* d_out, int out_size, void* d_ws, size_t ws_size,
                              hipStream_t stream) {
    if (ws_size < WS_FLOATS * sizeof(float)) return;

    const float* img    = (const float*)d_in[0];
    const float* stem_w = (const float*)d_in[1];
    const float* dw1_w  = (const float*)d_in[2];
    const float* pw1_w  = (const float*)d_in[3];
    const float* dw2_w  = (const float*)d_in[4];
    const float* pw2_w  = (const float*)d_in[5];
    const float* dw3_w  = (const float*)d_in[6];
    const float* pw3_w  = (const float*)d_in[7];
    const float* dw4_w  = (const float*)d_in[8];
    const float* pw4_w  = (const float*)d_in[9];
    const float* head_w = (const float*)d_in[10];
    const float* proj_w = (const float*)d_in[11];
    const float* proj_b = (const float*)d_in[12];
    const float* final_w= (const float*)d_in[13];
    const float* final_b= (const float*)d_in[14];
    float* ws  = (float*)d_ws;
    float* out = (float*)d_out;

    // TV Chambolle: 20 iterations in 2 register-resident launches (10+10).
    dim3 tvg1(12, 21, 4), tvg2(12, 19, 4);
    tv_reg<10, true,  false><<<tvg1, 512, 0, stream>>>(
        img, img, ws + O_PA,
        pw1_w, pw2_w, pw3_w, pw4_w, head_w, proj_w, proj_b, final_w, ws);
    tv_reg<10, false, true ><<<tvg2, 512, 0, stream>>>(
        img, ws + O_PA, ws + O_DEN,
        nullptr, nullptr, nullptr, nullptr, nullptr, nullptr, nullptr, nullptr, ws);

    // fused stem + dw1 + pw1 (den -> [B][64][128][128])
    stem_dw1_pw1<<<dim3(16, 16, 4), 256, 0, stream>>>(ws + O_DEN, stem_w, dw1_w,
                                                      ws + O_WT1, ws + O_A1);

    // backbone
    dw_kernel<64, 128><<<4096, 256, 0, stream>>>(ws + O_A1, dw2_w, ws + O_A2);
    pw_gemm<64, 1, 2, 128, false><<<dim3(64, 2, 8), 256, 0, stream>>>(ws + O_A2, ws + O_WT2, ws + O_PA, 4096);

    dw_reduce2_kernel<128, 64><<<2048, 256, 0, stream>>>(ws + O_PA, dw3_w, ws + O_A1);
    pw_gemm<128, 1, 2, 256, false><<<dim3(16, 4, 8), 256, 0, stream>>>(ws + O_A1, ws + O_WT3, ws + O_PA, 1024);

    dw_reduce2_kernel<256, 32><<<1024, 256, 0, stream>>>(ws + O_PA, dw4_w, ws + O_A2);
    pw_gemm<256, 1, 4, 512, false><<<dim3(4, 8, 16), 256, 0, stream>>>(ws + O_A2, ws + O_WT4, ws + O_PA, 256);

    // head 512->1280 full-K with fused silu+wcomb-dot epilogue -> 20KB partial field in A1
    head_fused<<<dim3(8, 20, 4), 256, 0, stream>>>(ws + O_PA, ws + O_WTH, ws + O_WCOMB, ws + O_A1);

    // fused partial-reduce + bilinear resize + 2-level Haar + bias
    resize_haar<<<256, 256, 0, stream>>>(ws + O_A1, ws + O_BCOMB, final_b, out);
}

// Round 6
// 239.001 us; speedup vs baseline: 1.0600x; 1.0011x over previous
//
#include <hip/hip_runtime.h>
#include <math.h>

// ---------------- problem constants ----------------
constexpr int BATCH = 4;
constexpr int IMG_H = 512, IMG_W = 512;
constexpr int IMG_HW = IMG_H * IMG_W;          // 262144
constexpr int PSTR = BATCH * IMG_HW;           // p-plane stride 1048576

// ---------------- workspace layout (floats) ----------------
constexpr size_t O_PA   = 0;                       // p ping [2][4][512][512] (also split-K partial arena)
constexpr size_t O_PB   = O_PA + 2 * (size_t)PSTR; // p pong
constexpr size_t O_DEN  = O_PB + 2 * (size_t)PSTR; // denoised [4][512][512]
constexpr size_t O_A1   = O_DEN + (size_t)PSTR;    // arena1 (8388608 floats; also head-partial field)
constexpr size_t O_A2   = O_A1 + 8388608;          // arena2 (2097152 floats)
constexpr size_t O_WT1  = O_A2 + 2097152;          // wT pw1  [32][64]
constexpr size_t O_WT2  = O_WT1 + 32 * 64;
constexpr size_t O_WT3  = O_WT2 + 64 * 128;
constexpr size_t O_WT4  = O_WT3 + 128 * 256;
constexpr size_t O_WTH  = O_WT4 + 256 * 512;
constexpr size_t O_WCOMB= O_WTH + 512 * 1280;      // [1280]
constexpr size_t O_BCOMB= O_WCOMB + 1280;          // [1]
constexpr size_t O_S    = O_BCOMB + 4;             // (unused now; kept for layout stability)
constexpr size_t WS_FLOATS = O_S + 1024;

// fast-math device helpers (1-ulp HW ops; validated absmax-neutral in R1)
__device__ __forceinline__ float fast_rcp(float x) { return __builtin_amdgcn_rcpf(x); }
__device__ __forceinline__ float fast_sqrt(float x) { return __builtin_amdgcn_sqrtf(x); }
__device__ __forceinline__ float silu_f(float x) {
    float e = __builtin_amdgcn_exp2f(-1.44269504088896f * x);
    return x * fast_rcp(1.0f + e);
}
__device__ __forceinline__ int clampi(int v, int lo, int hi) {
    return v < lo ? lo : (v > hi ? hi : v);
}

// ---------------- TV Chambolle: register-resident, shuffle-exchange ----------------
// (unchanged from R4: 1 barrier/stage, parity dbuf; R3: launch_bounds(512,8)
// -> 64 VGPR cap, 4 blocks/CU, single-occupancy-pass grid.)
template <int NST, bool FIRST, bool LAST>
__global__ __launch_bounds__(512, 8) void tv_reg(const float* __restrict__ img,
                                                 const float* __restrict__ pin,
                                                 float* __restrict__ pout,
                                                 const float* __restrict__ pw1,
                                                 const float* __restrict__ pw2,
                                                 const float* __restrict__ pw3,
                                                 const float* __restrict__ pw4,
                                                 const float* __restrict__ headw,
                                                 const float* __restrict__ projw,
                                                 const float* __restrict__ projb,
                                                 const float* __restrict__ finalw,
                                                 float* __restrict__ ws) {
    constexpr int ROWS = 6, NW = 8, HL = 10, TC = 44, TR = 28;
    constexpr int TVY = 19;
    __shared__ float bndP[2][512], bndO[2][512];

    if constexpr (FIRST) {
        if (blockIdx.y >= TVY) {
            // ---- prep branch: 96 blocks, grid-stride over 814 work tiles ----
            __shared__ float tt[32][33];
            const int tid = threadIdx.x;
            const int pid = ((blockIdx.y - TVY) * 4 + blockIdx.z) * 12 + blockIdx.x; // [0,96)
            for (int t = pid; t < 814; t += 96) {
                const float* src = nullptr; float* dst = nullptr;
                int C = 0, R = 0, tr = 0, tc = 0;
                if (t < 640) {        // head: 1280(oc) x 512(ic) -> [512][1280]
                    src = headw; dst = ws + O_WTH; R = 1280; C = 512; tr = t >> 4; tc = t & 15;
                } else if (t < 768) { // pw4: 512 x 256 -> [256][512]
                    int e = t - 640; src = pw4; dst = ws + O_WT4; R = 512; C = 256; tr = e >> 3; tc = e & 7;
                } else if (t < 800) { // pw3: 256 x 128 -> [128][256]
                    int e = t - 768; src = pw3; dst = ws + O_WT3; R = 256; C = 128; tr = e >> 2; tc = e & 3;
                } else if (t < 808) { // pw2: 128 x 64 -> [64][128]
                    int e = t - 800; src = pw2; dst = ws + O_WT2; R = 128; C = 64; tr = e >> 1; tc = e & 1;
                } else if (t < 810) { // pw1: 64 x 32 -> [32][64]
                    int e = t - 808; src = pw1; dst = ws + O_WT1; R = 64; C = 32; tr = e; tc = 0;
                }
                const int tx = tid & 31, ty = tid >> 5;       // 32 x 16
                __syncthreads();                              // WAR on tt across t-iterations
                if (src) {
#pragma unroll
                    for (int j = 0; j < 2; ++j)
                        tt[ty + j * 16][tx] =
                            src[(size_t)(tr * 32 + ty + j * 16) * C + tc * 32 + tx];
                }
                __syncthreads();
                if (src) {
#pragma unroll
                    for (int j = 0; j < 2; ++j)
                        dst[(size_t)(tc * 32 + ty + j * 16) * R + tr * 32 + tx] =
                            tt[tx][ty + j * 16];
                } else if (t < 813) {                         // wcomb chunks of 512
                    int k = (t - 810) * 512 + tid;
                    if (k < 1280) {
                        float a = 0.0f;
                        for (int ch = 0; ch < 64; ++ch)
                            a = fmaf(finalw[ch], projw[ch * 1280 + k], a);
                        ws[O_WCOMB + k] = a;
                    }
                } else {                                      // t == 813: bcomb
                    if (tid == 0) {
                        float a = 0.0f;
                        for (int ch = 0; ch < 64; ++ch) a = fmaf(finalw[ch], projb[ch], a);
                        ws[O_BCOMB] = a;
                    }
                }
            }
            return;
        }
    }

    const int tid = threadIdx.x;
    const int lane = tid & 63, w = tid >> 6;
    const int b = blockIdx.z;
    const int r0 = blockIdx.y * TR, c0 = blockIdx.x * TC;
    const int gj = c0 - HL + lane;
    const int gjc = clampi(gj, 0, 511);
    const int gib = r0 - HL + w * ROWS;
    const float* I = img + b * IMG_HW;
    const bool interior = (r0 - HL >= 1) && (r0 + NW * ROWS - HL <= 511) &&
                          (c0 - HL >= 1) && (c0 + 64 - HL <= 511);

    float rim[ROWS], rp0[ROWS], rp1[ROWS], ro[ROWS];
#pragma unroll
    for (int k = 0; k < ROWS; ++k) {
        int gi = clampi(gib + k, 0, 511);
        rim[k] = I[(gi << 9) + gjc];
    }
    if (!FIRST) {
        const float* P0 = pin + b * IMG_HW;
        const float* P1 = pin + PSTR + b * IMG_HW;
#pragma unroll
        for (int k = 0; k < ROWS; ++k) {
            int gi = clampi(gib + k, 0, 511);
            rp0[k] = P0[(gi << 9) + gjc];
            rp1[k] = P1[(gi << 9) + gjc];
        }
    }
    const bool gjpos = (gj > 0), gjlt = (gj < 511);

    int s0 = 0;
    if (FIRST) {
        // stage 0 specialized: p == 0  =>  out-field == img
        bndO[0][tid] = rim[0];
        __syncthreads();
        float odn = (w < NW - 1) ? bndO[0][tid + 64] : 0.0f;
        if (interior) {
#pragma unroll
            for (int k = 0; k < ROWS; ++k) {
                float oR = __shfl_down(rim[k], 1);
                float od = (k < ROWS - 1) ? rim[k + 1] : odn;
                float gy = od - rim[k];
                float gx = oR - rim[k];
                float inv = fast_rcp(fmaf(2.5f, fast_sqrt(fmaf(gy, gy, gx * gx)), 1.0f));
                rp0[k] = -0.25f * gy * inv;
                rp1[k] = -0.25f * gx * inv;
            }
        } else {
#pragma unroll
            for (int k = 0; k < ROWS; ++k) {
                float oR = __shfl_down(rim[k], 1);
                float od = (k < ROWS - 1) ? rim[k + 1] : odn;
                int gi = gib + k;
                float gy = (gi < 511) ? od - rim[k] : 0.0f;
                float gx = gjlt ? oR - rim[k] : 0.0f;
                float inv = fast_rcp(fmaf(2.5f, fast_sqrt(fmaf(gy, gy, gx * gx)), 1.0f));
                rp0[k] = -0.25f * gy * inv;
                rp1[k] = -0.25f * gx * inv;
            }
        }
        s0 = 1;
    }

    for (int s = s0; s < NST; ++s) {
        const int par = s & 1;
        float p1l0 = __shfl_up(rp1[0], 1);
        float partO = rim[0] - rp0[0] - rp1[0];
        if (interior) partO += p1l0;
        else if (gjpos) partO += p1l0;
        bndP[par][tid] = rp0[ROWS - 1];
        bndO[par][tid] = partO;
        __syncthreads();
        float pup0 = (w > 0) ? bndP[par][tid - 64] : 0.0f;
        float odn = (w < NW - 1) ? bndO[par][tid + 64] + rp0[ROWS - 1] : 0.0f;
        if (interior) {
            ro[0] = partO + pup0;
#pragma unroll
            for (int k = 1; k < ROWS; ++k) {
                float p1l = __shfl_up(rp1[k], 1);
                ro[k] = rim[k] - rp0[k] - rp1[k] + rp0[k - 1] + p1l;
            }
#pragma unroll
            for (int k = 0; k < ROWS; ++k) {
                float oR = __shfl_down(ro[k], 1);
                float od = (k < ROWS - 1) ? ro[k + 1] : odn;
                float gy = od - ro[k];
                float gx = oR - ro[k];
                float inv = fast_rcp(fmaf(2.5f, fast_sqrt(fmaf(gy, gy, gx * gx)), 1.0f));
                rp0[k] = (rp0[k] - 0.25f * gy) * inv;
                rp1[k] = (rp1[k] - 0.25f * gx) * inv;
            }
        } else {
            ro[0] = partO + ((gib > 0) ? pup0 : 0.0f);
#pragma unroll
            for (int k = 1; k < ROWS; ++k) {
                float p1l = __shfl_up(rp1[k], 1);
                float o = rim[k] - rp0[k] - rp1[k];
                if (gib + k > 0) o += rp0[k - 1];
                if (gjpos) o += p1l;
                ro[k] = o;
            }
#pragma unroll
            for (int k = 0; k < ROWS; ++k) {
                float oR = __shfl_down(ro[k], 1);
                float od = (k < ROWS - 1) ? ro[k + 1] : odn;
                int gi = gib + k;
                float gy = (gi < 511) ? od - ro[k] : 0.0f;
                float gx = gjlt ? oR - ro[k] : 0.0f;
                float inv = fast_rcp(fmaf(2.5f, fast_sqrt(fmaf(gy, gy, gx * gx)), 1.0f));
                rp0[k] = (rp0[k] - 0.25f * gy) * inv;
                rp1[k] = (rp1[k] - 0.25f * gx) * inv;
            }
        }
    }

    const bool cst = (lane >= HL && lane < HL + TC && gj < 512);
    if (LAST) {
        constexpr int epar = NST & 1;
        bndP[epar][tid] = rp0[ROWS - 1];
        __syncthreads();
        float pup0 = (w > 0) ? bndP[epar][tid - 64] : 0.0f;
        float* D = pout + b * IMG_HW;
#pragma unroll
        for (int k = 0; k < ROWS; ++k) {
            float p1l = __shfl_up(rp1[k], 1);
            int gi = gib + k;
            int rk = w * ROWS + k;
            float o = rim[k] - rp0[k] - rp1[k];
            float pup = (k > 0) ? rp0[k - 1] : pup0;
            if (gi > 0) o += pup;
            if (gjpos) o += p1l;
            if (rk >= HL && rk < HL + TR && cst && gi < 512) D[(gi << 9) + gj] = o;
        }
    } else {
        float* Q0 = pout + b * IMG_HW;
        float* Q1 = pout + PSTR + b * IMG_HW;
#pragma unroll
        for (int k = 0; k < ROWS; ++k) {
            int rk = w * ROWS + k;
            int gi = gib + k;
            if (rk >= HL && rk < HL + TR && cst && gi < 512) {
                Q0[(gi << 9) + gj] = rp0[k];
                Q1[(gi << 9) + gj] = rp1[k];
            }
        }
    }
}

// ---------------- fused stem (3x3 s2 + SiLU) + dw1 (3x3 s2 + SiLU) + pw1 (1x1 32->64 + SiLU) ----
__global__ __launch_bounds__(256) void stem_dw1_pw1(const float* __restrict__ den,
                                                    const float* __restrict__ stemw,
                                                    const float* __restrict__ dw1w,
                                                    const float* __restrict__ pw1T,
                                                    float* __restrict__ out) {
    __shared__ float sDen[35 * 36];
    __shared__ float sStem[8 * 323];   // 8 ch x (17 rows x stride 19)
    __shared__ float sDw[32 * 64];     // dw1 out: [ic][px], px = dy*8+dx
    __shared__ float sW[576];
    __shared__ __align__(16) float sWp[2048];  // pw1T [ic][oc]
    const int tid = threadIdx.x;
    const int b = blockIdx.z;
    const int r0 = blockIdx.y * 32, c0 = blockIdx.x * 32;
    const float* D = den + b * IMG_HW;
    for (int e = tid; e < 576; e += 256) sW[e] = (e < 288) ? stemw[e] : dw1w[e - 288];
    for (int e = tid; e < 2048; e += 256) sWp[e] = pw1T[e];
    for (int e = tid; e < 35 * 35; e += 256) {
        int li = e / 35, lj = e % 35;
        int gi = r0 - 3 + li, gjj = c0 - 3 + lj;
        sDen[li * 36 + lj] = (gi >= 0 && gjj >= 0) ? D[(gi << 9) + gjj] : 0.0f;
    }
    __syncthreads();

    for (int g = 0; g < 4; ++g) {
        if (g) __syncthreads();
        for (int e = tid; e < 2312; e += 256) {      // 289 pos x 8 ch
            int pos = e >> 3, cl = e & 7;
            int sy = pos / 17, sx = pos % 17;
            int c = 8 * g + cl;
            const float* wc = &sW[c * 9];
            const float* dbase = &sDen[(2 * sy) * 36 + 2 * sx];
            float a = 0.0f;
#pragma unroll
            for (int ky = 0; ky < 3; ++ky)
#pragma unroll
                for (int kx = 0; kx < 3; ++kx)
                    a = fmaf(wc[ky * 3 + kx], dbase[ky * 36 + kx], a);
            sStem[cl * 323 + sy * 19 + sx] = silu_f(a);
        }
        __syncthreads();
        for (int e = tid; e < 512; e += 256) {
            int cl = e >> 6, dy = (e >> 3) & 7, dx = e & 7;
            int c = 8 * g + cl;
            float acc = 0.0f;
#pragma unroll
            for (int ky = 0; ky < 3; ++ky)
#pragma unroll
                for (int kx = 0; kx < 3; ++kx) {
                    int sgy = (r0 >> 1) - 1 + 2 * dy + ky;
                    int sgx = (c0 >> 1) - 1 + 2 * dx + kx;
                    float v = (sgy >= 0 && sgx >= 0)
                        ? sStem[cl * 323 + (2 * dy + ky) * 19 + 2 * dx + kx] : 0.0f;
                    acc = fmaf(sW[288 + c * 9 + ky * 3 + kx], v, acc);
                }
            sDw[c * 64 + (dy << 3) + dx] = silu_f(acc);
        }
    }
    __syncthreads();

    const int px = tid & 63, oc0 = (tid >> 6) * 16;
    float acc[16];
#pragma unroll
    for (int j = 0; j < 16; ++j) acc[j] = 0.0f;
    for (int ic = 0; ic < 32; ++ic) {
        float v = sDw[ic * 64 + px];
        const float* wr = &sWp[ic * 64 + oc0];
#pragma unroll
        for (int q = 0; q < 4; ++q) {
            float4 w4 = *(const float4*)(wr + q * 4);
            acc[q * 4 + 0] = fmaf(v, w4.x, acc[q * 4 + 0]);
            acc[q * 4 + 1] = fmaf(v, w4.y, acc[q * 4 + 1]);
            acc[q * 4 + 2] = fmaf(v, w4.z, acc[q * 4 + 2]);
            acc[q * 4 + 3] = fmaf(v, w4.w, acc[q * 4 + 3]);
        }
    }
    const int gpos = ((r0 >> 2) + (px >> 3)) * 128 + (c0 >> 2) + (px & 7);
    float* ob = out + (size_t)b * 64 * 16384 + (size_t)oc0 * 16384 + gpos;
#pragma unroll
    for (int j = 0; j < 16; ++j) ob[(size_t)j * 16384] = silu_f(acc[j]);
}

// ---------------- depthwise 3x3 s2 pad1 + SiLU ----------------
template <int C, int HIN>
__global__ __launch_bounds__(256) void dw_kernel(const float* __restrict__ in,
                                                 const float* __restrict__ w,
                                                 float* __restrict__ out) {
    constexpr int HO = HIN / 2;
    int t = blockIdx.x * 256 + threadIdx.x;       // B*C*HO*HO
    int x = t % HO;
    int y = (t / HO) % HO;
    int c = (t / (HO * HO)) % C;
    int b = t / (HO * HO * C);
    const float* I = in + ((size_t)(b * C + c)) * (HIN * HIN);
    const float* wc = w + c * 9;
    int iy = 2 * y - 1, ix = 2 * x - 1;
    float acc = 0.0f;
#pragma unroll
    for (int ky = 0; ky < 3; ++ky)
#pragma unroll
        for (int kx = 0; kx < 3; ++kx) {
            int yy = iy + ky, xx = ix + kx;
            float vv = (yy >= 0 && xx >= 0) ? I[yy * HIN + xx] : 0.0f;
            acc = fmaf(wc[ky * 3 + kx], vv, acc);
        }
    out[t] = silu_f(acc);
}

// ---------------- depthwise 3x3 s2 + fused 2-way split-K reduce + SiLU input ----------------
template <int C, int HIN>
__global__ __launch_bounds__(256) void dw_reduce2_kernel(const float* __restrict__ part,
                                                         const float* __restrict__ w,
                                                         float* __restrict__ out) {
    constexpr int HO = HIN / 2;
    int t = blockIdx.x * 256 + threadIdx.x;
    int x = t % HO;
    int y = (t / HO) % HO;
    int c = (t / (HO * HO)) % C;
    int b = t / (HO * HO * C);
    const float* Ia = part + ((size_t)(b * C + c)) * (HIN * HIN);
    const float* Ib = Ia + (size_t)BATCH * C * HIN * HIN;
    const float* wc = w + c * 9;
    int iy = 2 * y - 1, ix = 2 * x - 1;
    float acc = 0.0f;
#pragma unroll
    for (int ky = 0; ky < 3; ++ky)
#pragma unroll
        for (int kx = 0; kx < 3; ++kx) {
            int yy = iy + ky, xx = ix + kx;
            float vv = 0.0f;
            if (yy >= 0 && xx >= 0) {
                int o = yy * HIN + xx;
                vv = silu_f(Ia[o] + Ib[o]);
            }
            acc = fmaf(wc[ky * 3 + kx], vv, acc);
        }
    out[t] = silu_f(acc);
}

// ---------------- pointwise 1x1 conv: double-buffered, split-K GEMM ----------------
template <int ICT, int NSIN, int NSPLIT, int OC, bool SILU>
__global__ __launch_bounds__(256) void pw_gemm(const float* __restrict__ in,
                                               const float* __restrict__ wT,
                                               float* __restrict__ out,
                                               int HW) {
    constexpr int KC = 32, TP = 64, TOC = 64, OPT = 4, PPT = 4;
    constexpr int KS = ICT / NSPLIT;
    constexpr int NC = KS / KC;
    constexpr int NOG = TOC / OPT;                // 16
    constexpr int PV4 = KC * TP / 4 / 256;        // 2 float4/thread (px)
    constexpr int WV4 = KC * TOC / 4 / 256;       // 2 float4/thread (w)
    static_assert(KS % KC == 0, "split");
    __shared__ __align__(16) float sPx[2][KC * TP];
    __shared__ __align__(16) float sW[2][KC * TOC];
    const int tid = threadIdx.x;
    const int zb = blockIdx.z;
    const int b = zb / NSPLIT, ks = zb % NSPLIT;
    const int p0 = blockIdx.x * TP;
    const int oc0 = blockIdx.y * TOC;
    const int ocg = tid % NOG, pxg = tid / NOG;   // pxg in [0,16)
    const size_t instride = (size_t)BATCH * ICT * HW;
    const float* gin0 = in + ((size_t)b * ICT + ks * KS) * HW + p0;
    const float* gw0  = wT + ((size_t)(ks * KS)) * OC + oc0;

    float4 rp[PV4], rw[WV4];
    auto load_chunk = [&](int cc) {
        const float* gin = gin0 + (size_t)cc * KC * HW;
#pragma unroll
        for (int i = 0; i < PV4; ++i) {
            int e = tid + i * 256;
            int row = e / (TP / 4), col = e % (TP / 4);
            const float* base = gin + (size_t)row * HW + col * 4;
            float4 a = *(const float4*)base;
#pragma unroll
            for (int s = 1; s < NSIN; ++s) {
                float4 t4 = *(const float4*)(base + (size_t)s * instride);
                a.x += t4.x; a.y += t4.y; a.z += t4.z; a.w += t4.w;
            }
            if (NSIN > 1) {
                a.x = silu_f(a.x); a.y = silu_f(a.y);
                a.z = silu_f(a.z); a.w = silu_f(a.w);
            }
            rp[i] = a;
        }
        const float* gw = gw0 + (size_t)cc * KC * OC;
#pragma unroll
        for (int i = 0; i < WV4; ++i) {
            int e = tid + i * 256;
            int row = e / (TOC / 4), col = e % (TOC / 4);
            rw[i] = *(const float4*)(gw + (size_t)row * OC + col * 4);
        }
    };
    auto store_chunk = [&](int buf) {
#pragma unroll
        for (int i = 0; i < PV4; ++i) ((float4*)sPx[buf])[tid + i * 256] = rp[i];
#pragma unroll
        for (int i = 0; i < WV4; ++i) ((float4*)sW[buf])[tid + i * 256] = rw[i];
    };

    float acc[OPT][PPT];
#pragma unroll
    for (int o = 0; o < OPT; ++o)
#pragma unroll
        for (int p = 0; p < PPT; ++p) acc[o][p] = 0.0f;

    load_chunk(0);
    store_chunk(0);
    __syncthreads();
    for (int cc = 0; cc < NC; ++cc) {
        if (cc + 1 < NC) load_chunk(cc + 1);
        const int buf = cc & 1;
#pragma unroll 4
        for (int k = 0; k < KC; ++k) {
            float4 pv = *(const float4*)&sPx[buf][k * TP + pxg * PPT];
            float4 wv = *(const float4*)&sW[buf][k * TOC + ocg * OPT];
            float w0 = wv.x, w1 = wv.y, w2 = wv.z, w3 = wv.w;
            acc[0][0] = fmaf(pv.x, w0, acc[0][0]);
            acc[0][1] = fmaf(pv.y, w0, acc[0][1]);
            acc[0][2] = fmaf(pv.z, w0, acc[0][2]);
            acc[0][3] = fmaf(pv.w, w0, acc[0][3]);
            acc[1][0] = fmaf(pv.x, w1, acc[1][0]);
            acc[1][1] = fmaf(pv.y, w1, acc[1][1]);
            acc[1][2] = fmaf(pv.z, w1, acc[1][2]);
            acc[1][3] = fmaf(pv.w, w1, acc[1][3]);
            acc[2][0] = fmaf(pv.x, w2, acc[2][0]);
            acc[2][1] = fmaf(pv.y, w2, acc[2][1]);
            acc[2][2] = fmaf(pv.z, w2, acc[2][2]);
            acc[2][3] = fmaf(pv.w, w2, acc[2][3]);
            acc[3][0] = fmaf(pv.x, w3, acc[3][0]);
            acc[3][1] = fmaf(pv.y, w3, acc[3][1]);
            acc[3][2] = fmaf(pv.z, w3, acc[3][2]);
            acc[3][3] = fmaf(pv.w, w3, acc[3][3]);
        }
        if (cc + 1 < NC) {
            store_chunk((cc + 1) & 1);
            __syncthreads();
        }
    }

    float* ob;
    if (NSPLIT == 1)
        ob = out + ((size_t)(b * OC + oc0 + ocg * OPT)) * HW + p0 + pxg * PPT;
    else
        ob = out + (((size_t)(ks * BATCH + b)) * OC + oc0 + ocg * OPT) * HW + p0 + pxg * PPT;
#pragma unroll
    for (int o = 0; o < OPT; ++o) {
        float4 r;
        r.x = SILU ? silu_f(acc[o][0]) : acc[o][0];
        r.y = SILU ? silu_f(acc[o][1]) : acc[o][1];
        r.z = SILU ? silu_f(acc[o][2]) : acc[o][2];
        r.w = SILU ? silu_f(acc[o][3]) : acc[o][3];
        *(float4*)(ob + (size_t)o * HW) = r;
    }
}

// ---------------- head GEMM 512->1280, full-K, fused silu+wcomb-dot epilogue ----------------
// R6: 512 threads/block, K split ACROSS the two 256-thread groups (g=tid>>8
// owns K in [g*256, g*256+256), NC=8 chunks each, private dbuf LDS), then an
// LDS reduce combines the two partial accs BEFORE the silu+wcomb epilogue.
// Fixes R5's latency stall (45.7us @ 20% occupancy, VALUBusy 30%): waves/CU
// 6.4 -> 20, serial chunk-barriers 16 -> 8(+2). K-reduce aliases staging LDS.
__global__ __launch_bounds__(512) void head_fused(const float* __restrict__ in,
                                                  const float* __restrict__ wT,
                                                  const float* __restrict__ wcomb,
                                                  float* __restrict__ partial) {
    constexpr int ICT = 512, KC = 32, TP = 32, TOC = 64, OC = 1280, HW = 256;
    constexpr int NCG = 8;                        // chunks per group (K half = 256)
    // LDS carve: pxBuf [2g][2buf][1024] | wBuf [2g][2buf][2048] | dotred [512]
    __shared__ __align__(16) float smem[4096 + 8192 + 512];
    float* pxBuf = smem;
    float* wBuf  = smem + 4096;
    float* dotred= smem + 12288;
    float* kred  = smem;                          // alias (post-barrier): [256][8]
    const int tid = threadIdx.x;
    const int g = tid >> 8, lt = tid & 255;
    const int b = blockIdx.z;
    const int p0 = blockIdx.x * TP;
    const int oc0 = blockIdx.y * TOC;
    const int ocg = lt & 15, pxg = lt >> 4;       // ocg in [0,16), pxg in [0,16)
    const size_t instride = (size_t)BATCH * ICT * HW;   // pw4 split stride
    const float* gin0 = in + (size_t)b * ICT * HW + p0;

    float4 rp, rw[2];
    auto load_chunk = [&](int cc) {               // cc in [0,8): group-local chunk
        const float* gin = gin0 + (size_t)(g * NCG + cc) * KC * HW;
        {
            int row = lt >> 3, col = lt & 7;      // 32 rows x 8 float4
            const float* base = gin + (size_t)row * HW + col * 4;
            float4 a = *(const float4*)base;
#pragma unroll
            for (int s = 1; s < 4; ++s) {
                float4 t4 = *(const float4*)(base + (size_t)s * instride);
                a.x += t4.x; a.y += t4.y; a.z += t4.z; a.w += t4.w;
            }
            a.x = silu_f(a.x); a.y = silu_f(a.y);
            a.z = silu_f(a.z); a.w = silu_f(a.w);
            rp = a;
        }
        const float* gw = wT + (size_t)(g * NCG + cc) * KC * OC + oc0;
#pragma unroll
        for (int i = 0; i < 2; ++i) {
            int e = lt + i * 256;
            int row = e >> 4, col = e & 15;       // 32 rows x 16 float4
            rw[i] = *(const float4*)(gw + (size_t)row * OC + col * 4);
        }
    };
    auto store_chunk = [&](int buf) {
        ((float4*)(pxBuf + (g * 2 + buf) * 1024))[lt] = rp;
#pragma unroll
        for (int i = 0; i < 2; ++i)
            ((float4*)(wBuf + (g * 2 + buf) * 2048))[lt + i * 256] = rw[i];
    };

    float acc[4][2];
#pragma unroll
    for (int o = 0; o < 4; ++o) { acc[o][0] = 0.0f; acc[o][1] = 0.0f; }

    load_chunk(0);
    store_chunk(0);
    __syncthreads();
    for (int cc = 0; cc < NCG; ++cc) {
        if (cc + 1 < NCG) load_chunk(cc + 1);
        const float* sp = pxBuf + (g * 2 + (cc & 1)) * 1024;
        const float* sw = wBuf + (g * 2 + (cc & 1)) * 2048;
#pragma unroll 4
        for (int k = 0; k < KC; ++k) {
            float2 pv = *(const float2*)&sp[k * TP + pxg * 2];
            float4 wv = *(const float4*)&sw[k * TOC + ocg * 4];
            acc[0][0] = fmaf(pv.x, wv.x, acc[0][0]);
            acc[0][1] = fmaf(pv.y, wv.x, acc[0][1]);
            acc[1][0] = fmaf(pv.x, wv.y, acc[1][0]);
            acc[1][1] = fmaf(pv.y, wv.y, acc[1][1]);
            acc[2][0] = fmaf(pv.x, wv.z, acc[2][0]);
            acc[2][1] = fmaf(pv.y, wv.z, acc[2][1]);
            acc[3][0] = fmaf(pv.x, wv.w, acc[3][0]);
            acc[3][1] = fmaf(pv.y, wv.w, acc[3][1]);
        }
        if (cc + 1 < NCG) {
            store_chunk((cc + 1) & 1);
            __syncthreads();
        }
    }

    // combine the two K-halves: group 1 exports accs (aliasing staging LDS),
    // group 0 adds and runs the epilogue.
    __syncthreads();                              // all staging reads done before alias
    if (g == 1) {
#pragma unroll
        for (int o = 0; o < 4; ++o) {
            kred[lt * 8 + o * 2 + 0] = acc[o][0];
            kred[lt * 8 + o * 2 + 1] = acc[o][1];
        }
    }
    __syncthreads();
    if (g == 0) {
#pragma unroll
        for (int o = 0; o < 4; ++o) {
            acc[o][0] += kred[lt * 8 + o * 2 + 0];
            acc[o][1] += kred[lt * 8 + o * 2 + 1];
        }
        // epilogue: silu + wcomb dot over this thread's 4 ocs
        float4 wc4 = *(const float4*)(wcomb + oc0 + ocg * 4);
#pragma unroll
        for (int p = 0; p < 2; ++p) {
            float v = wc4.x * silu_f(acc[0][p]);
            v = fmaf(wc4.y, silu_f(acc[1][p]), v);
            v = fmaf(wc4.z, silu_f(acc[2][p]), v);
            v = fmaf(wc4.w, silu_f(acc[3][p]), v);
            dotred[(pxg * 2 + p) * 16 + ocg] = v;
        }
    }
    __syncthreads();
    if (tid < 32) {
        float a = 0.0f;
#pragma unroll
        for (int gg = 0; gg < 16; ++gg) a += dotred[tid * 16 + gg];
        partial[((size_t)blockIdx.y * 4 + b) * 256 + p0 + tid] = a;
    }
}

// ---------------- fused 20-way partial reduce + bilinear(16->512) + 2-level Haar LL + bias ----
__global__ __launch_bounds__(256) void resize_haar(const float* __restrict__ partial,
                                                   const float* __restrict__ bcomb,
                                                   const float* __restrict__ finalb,
                                                   float* __restrict__ out) {
    __shared__ float sS[256];
    int t = blockIdx.x * 256 + threadIdx.x;       // 4*128*128; each block = one b
    int c = t & 127, r = (t >> 7) & 127, b = t >> 14;
    {   // s[b][px] = bcomb + sum over 20 oc-block partials
        float a = bcomb[0];
        const float* P = partial + (size_t)b * 256 + threadIdx.x;
        for (int y = 0; y < 20; ++y) a += P[(size_t)y * 1024];
        sS[threadIdx.x] = a;
    }
    __syncthreads();
    const float* S = sS;
    float acc = 0.0f;
#pragma unroll
    for (int j = 0; j < 4; ++j) {
        float sy = ((4 * r + j) + 0.5f) * (1.0f / 32.0f) - 0.5f;
        int y0 = (int)floorf(sy);
        float fy = sy - (float)y0;
        int ya = y0 < 0 ? 0 : y0;
        int yb = (y0 + 1) > 15 ? 15 : (y0 + 1);
#pragma unroll
        for (int i = 0; i < 4; ++i) {
            float sx = ((4 * c + i) + 0.5f) * (1.0f / 32.0f) - 0.5f;
            int x0 = (int)floorf(sx);
            float fx = sx - (float)x0;
            int xa = x0 < 0 ? 0 : x0;
            int xb = (x0 + 1) > 15 ? 15 : (x0 + 1);
            float v0 = S[ya * 16 + xa] * (1.0f - fx) + S[ya * 16 + xb] * fx;
            float v1 = S[yb * 16 + xa] * (1.0f - fx) + S[yb * 16 + xb] * fx;
            acc += v0 * (1.0f - fy) + v1 * fy;
        }
    }
    out[t] = 0.25f * acc + finalb[0];
}

// ---------------- launch ----------------
extern "C" void kernel_launch(void* const* d_in, const int* in_sizes, int n_in,
                              void* d_out, int out_size, void* d_ws, size_t ws_size,
                              hipStream_t stream) {
    if (ws_size < WS_FLOATS * sizeof(float)) return;

    const float* img    = (const float*)d_in[0];
    const float* stem_w = (const float*)d_in[1];
    const float* dw1_w  = (const float*)d_in[2];
    const float* pw1_w  = (const float*)d_in[3];
    const float* dw2_w  = (const float*)d_in[4];
    const float* pw2_w  = (const float*)d_in[5];
    const float* dw3_w  = (const float*)d_in[6];
    const float* pw3_w  = (const float*)d_in[7];
    const float* dw4_w  = (const float*)d_in[8];
    const float* pw4_w  = (const float*)d_in[9];
    const float* head_w = (const float*)d_in[10];
    const float* proj_w = (const float*)d_in[11];
    const float* proj_b = (const float*)d_in[12];
    const float* final_w= (const float*)d_in[13];
    const float* final_b= (const float*)d_in[14];
    float* ws  = (float*)d_ws;
    float* out = (float*)d_out;

    // TV Chambolle: 20 iterations in 2 register-resident launches (10+10).
    dim3 tvg1(12, 21, 4), tvg2(12, 19, 4);
    tv_reg<10, true,  false><<<tvg1, 512, 0, stream>>>(
        img, img, ws + O_PA,
        pw1_w, pw2_w, pw3_w, pw4_w, head_w, proj_w, proj_b, final_w, ws);
    tv_reg<10, false, true ><<<tvg2, 512, 0, stream>>>(
        img, ws + O_PA, ws + O_DEN,
        nullptr, nullptr, nullptr, nullptr, nullptr, nullptr, nullptr, nullptr, ws);

    // fused stem + dw1 + pw1 (den -> [B][64][128][128])
    stem_dw1_pw1<<<dim3(16, 16, 4), 256, 0, stream>>>(ws + O_DEN, stem_w, dw1_w,
                                                      ws + O_WT1, ws + O_A1);

    // backbone
    dw_kernel<64, 128><<<4096, 256, 0, stream>>>(ws + O_A1, dw2_w, ws + O_A2);
    pw_gemm<64, 1, 2, 128, false><<<dim3(64, 2, 8), 256, 0, stream>>>(ws + O_A2, ws + O_WT2, ws + O_PA, 4096);

    dw_reduce2_kernel<128, 64><<<2048, 256, 0, stream>>>(ws + O_PA, dw3_w, ws + O_A1);
    pw_gemm<128, 1, 2, 256, false><<<dim3(16, 4, 8), 256, 0, stream>>>(ws + O_A1, ws + O_WT3, ws + O_PA, 1024);

    dw_reduce2_kernel<256, 32><<<1024, 256, 0, stream>>>(ws + O_PA, dw4_w, ws + O_A2);
    pw_gemm<256, 1, 4, 512, false><<<dim3(4, 8, 16), 256, 0, stream>>>(ws + O_A2, ws + O_WT4, ws + O_PA, 256);

    // head 512->1280 full-K (block-internal K-split) + fused silu+wcomb-dot -> 20KB field in A1
    head_fused<<<dim3(8, 20, 4), 512, 0, stream>>>(ws + O_PA, ws + O_WTH, ws + O_WCOMB, ws + O_A1);

    // fused partial-reduce + bilinear resize + 2-level Haar + bias
    resize_haar<<<256, 256, 0, stream>>>(ws + O_A1, ws + O_BCOMB, final_b, out);
}